// Round 4
// baseline (2761.839 us; speedup 1.0000x reference)
//
#include <hip/hip_runtime.h>

// Chambolle-Pock anisotropic TV prox. B=8, H=W=256, 200 iters, fp32.
//
// Round 4: PERSISTENT kernel (single launch). Same trapezoid structure as
// round 3 (interior 32x64, halo 8, region 48x80, 8 iters/phase, 25 phases,
// 256 blocks = 1/CU), but state lives in registers across all phases:
//  - f/lam -> bf/ly/ldn loaded ONCE (incl. the phantom-pad lam fixes).
//  - phase boundary publishes only the 8-wide interior FRAME (cells a
//    neighbor can see) of u/ub/p/q to double-buffered global arrays, then
//    reloads only the halo groups from the neighbors' frames.
//  - inter-block sync = per-block phase flags + 8-neighbor spin
//    (device-scope atomics, release/acquire, __threadfence both sides).
//    Double buffering makes reuse safe: block X overwrites buf[par] at
//    phase ph+2 only after seeing neighbor flags >= ph+2, and a neighbor
//    flags ph+2 only after it finished READING phase-ph data.
//  - deadlock-free without cooperative launch: grid=256 <= 256 CUs, each
//    CU hosts >=1 block (LDS 37.7KB, __launch_bounds__(512,2) => <=256
//    VGPR), so all blocks are co-resident.
//  - flags alias core-center cells of the parity-0 u buffer: publish
//    writes FRAME cells only, reload reads FRAME cells only, so those
//    cells are never touched by data; 0xAA ws-poison = negative int =
//    "not ready", so no init pass is needed.

#define Hc 256
#define Wc 256
#define Bc 8
#define NPIX (Bc * Hc * Wc)          // 524288

#define RROWS 48
#define RCOLS 80
#define IROWS 32
#define ICOLS 64
#define HALO  8
#define TITER 8
#define NPHASE 25
#define NGRP  (RROWS * (RCOLS / 4))  // 960 groups of 4 px
#define BLK   512
#define LSTR  84                      // LDS row stride (floats)

constexpr float TAUc = 0.35355339f;
constexpr float SIGc = 0.35355339f;
constexpr float Ac_  = 1.0f / (1.0f + TAUc);  // 1/(1+tau)
constexpr float Bq_  = TAUc * Ac_;            // tau/(1+tau)

__device__ __forceinline__ float2 gld2(const float* p, int gi, int gj) {
    if ((unsigned)gi < (unsigned)Hc && (unsigned)gj < (unsigned)Wc)
        return *(const float2*)(p + (gi << 8) + gj);
    return make_float2(0.f, 0.f);
}
__device__ __forceinline__ float gld1(const float* p, int gi, int gj) {
    if ((unsigned)gi < (unsigned)Hc && (unsigned)gj < (unsigned)Wc)
        return p[(gi << 8) + gj];
    return 0.f;
}

// flag cell: core center of block's interior in the parity-0 u buffer.
// Core cells are never stored (frame-only publish) nor loaded (halo reload
// touches only neighbor frames), so this aliasing is safe.
__device__ __forceinline__ int flag_idx(int blk) {
    const int b = blk >> 5, ti = (blk >> 2) & 7, tj = blk & 3;
    return b * (Hc * Wc) + ((ti * IROWS + 16) << 8) + (tj * ICOLS + 32);
}

__global__ __launch_bounds__(BLK, 2)
void tv_persist(const float* __restrict__ f, const float* __restrict__ lam,
                float* __restrict__ out, float* __restrict__ ws)
{
    __shared__ float s_ub[RROWS + 2][LSTR];
    __shared__ float s_p [RROWS + 2][LSTR];
    __shared__ float s_qe[RROWS][21];

    const int t   = threadIdx.x;
    const int blk = blockIdx.x;            // 0..255
    const int b   = blk >> 5;
    const int rem = blk & 31;
    const int ti  = rem >> 2;              // 0..7
    const int tj  = rem & 3;               // 0..3
    const int gi0 = ti * IROWS - HALO;
    const int gj0 = tj * ICOLS - HALO;
    const int boff = b * (Hc * Wc);

    const float* fb = f   + boff;
    const float* lb = lam + boff;

    float* Gu [2] = { ws + 0 * (size_t)NPIX, ws + 4 * (size_t)NPIX };
    float* Gub[2] = { ws + 1 * (size_t)NPIX, ws + 5 * (size_t)NPIX };
    float* Gp [2] = { ws + 2 * (size_t)NPIX, ws + 6 * (size_t)NPIX };
    float* Gq [2] = { ws + 3 * (size_t)NPIX, ws + 7 * (size_t)NPIX };
    int* flags = (int*)ws;                 // aliases Gu[0] core centers

    // neighbor assignment for threads 0..7
    int nbr = -1, nfidx = 0;
    if (t < 8) {
        const int DI[8] = {-1,-1,-1, 0, 0, 1, 1, 1};
        const int DJ[8] = {-1, 0, 1,-1, 1,-1, 0, 1};
        const int nti = ti + DI[t], ntj = tj + DJ[t];
        if (nti >= 0 && nti < 8 && ntj >= 0 && ntj < 4) {
            nbr   = (b << 5) | (nti << 2) | ntj;
            nfidx = flag_idx(nbr);
        }
    }
    const int myfidx = flag_idx(blk);

    float u[2][4], bf[2][4], ub[2][4], p[2][4], q[2][4], ly[2][4], ldn[2][4];
    int   rr[2], cg[2], c0[2];
    bool  act[2], intr[2], frame[2];

    // ---------------- one-time load / init (iteration 0 state) ----------------
    #pragma unroll
    for (int s = 0; s < 2; ++s) {
        const int gid = t + s * BLK;
        act[s] = (gid < NGRP);
        int row = gid / 20;
        int cgv = gid - row * 20;
        rr[s] = row; cg[s] = cgv; c0[s] = cgv * 4;
        const int ir  = row - HALO;        // interior-local row
        const int icg = cgv - 2;           // interior-local col group
        intr[s]  = act[s] && ((unsigned)ir < IROWS) && ((unsigned)icg < 16u);
        frame[s] = intr[s] && (ir < 8 || ir >= 24 || icg < 2 || icg >= 14);
        if (!act[s]) continue;

        const int gi = gi0 + row;
        const int gj = gj0 + c0[s];

        float2 a0 = gld2(fb, gi, gj), a1 = gld2(fb, gi, gj + 2);
        const float fv0 = a0.x, fv1 = a0.y, fv2 = a1.x, fv3 = a1.y;
        bf[s][0] = Bq_ * fv0; bf[s][1] = Bq_ * fv1;
        bf[s][2] = Bq_ * fv2; bf[s][3] = Bq_ * fv3;

        a0 = gld2(lb, gi, gj); a1 = gld2(lb, gi, gj + 2);
        const float le = gld1(lb, gi, gj + 4);
        ly[s][0] = a0.y; ly[s][1] = a1.x; ly[s][2] = a1.y; ly[s][3] = le;
        a0 = gld2(lb, gi + 1, gj); a1 = gld2(lb, gi + 1, gj + 2);
        ldn[s][0] = a0.x; ldn[s][1] = a0.y; ldn[s][2] = a1.x; ldn[s][3] = a1.y;

        // phantom-pad fix: reference pads p[-1,:]=0 and q[:,-1]=0; shifted
        // clamp bounds (lam[i+1], lam[j+1]) are in-image there -> zero them.
        if (gi < 0) { ldn[s][0] = ldn[s][1] = ldn[s][2] = ldn[s][3] = 0.f; }
        #pragma unroll
        for (int e = 0; e < 4; ++e) if (gj + e < 0) ly[s][e] = 0.f;

        u[s][0] = ub[s][0] = fv0; u[s][1] = ub[s][1] = fv1;
        u[s][2] = ub[s][2] = fv2; u[s][3] = ub[s][3] = fv3;
        p[s][0] = p[s][1] = p[s][2] = p[s][3] = 0.f;
        q[s][0] = q[s][1] = q[s][2] = q[s][3] = 0.f;

        *(float4*)&s_ub[row + 1][c0[s]] = make_float4(ub[s][0], ub[s][1], ub[s][2], ub[s][3]);
        *(float4*)&s_p [row + 1][c0[s]] = make_float4(p[s][0], p[s][1], p[s][2], p[s][3]);
        s_qe[row][cgv + 1] = q[s][3];
    }
    __syncthreads();

    // ---------------- phase loop ----------------
    for (int ph = 0; ph < NPHASE; ++ph) {
        // ---- 8 fused iterations (identical to round 3) ----
        for (int k = 0; k < TITER; ++k) {
            #pragma unroll
            for (int s = 0; s < 2; ++s) {
                if (!act[s]) continue;
                const int r = rr[s], col0 = c0[s];
                float4 ubdn = *(const float4*)&s_ub[r + 2][col0];
                float  ubre = s_ub[r + 1][col0 + 4];

                float v;
                v = fmaf(SIGc, ubdn.x - ub[s][0], p[s][0]); p[s][0] = fminf(fmaxf(v, -ldn[s][0]), ldn[s][0]);
                v = fmaf(SIGc, ubdn.y - ub[s][1], p[s][1]); p[s][1] = fminf(fmaxf(v, -ldn[s][1]), ldn[s][1]);
                v = fmaf(SIGc, ubdn.z - ub[s][2], p[s][2]); p[s][2] = fminf(fmaxf(v, -ldn[s][2]), ldn[s][2]);
                v = fmaf(SIGc, ubdn.w - ub[s][3], p[s][3]); p[s][3] = fminf(fmaxf(v, -ldn[s][3]), ldn[s][3]);

                v = fmaf(SIGc, ub[s][1] - ub[s][0], q[s][0]); q[s][0] = fminf(fmaxf(v, -ly[s][0]), ly[s][0]);
                v = fmaf(SIGc, ub[s][2] - ub[s][1], q[s][1]); q[s][1] = fminf(fmaxf(v, -ly[s][1]), ly[s][1]);
                v = fmaf(SIGc, ub[s][3] - ub[s][2], q[s][2]); q[s][2] = fminf(fmaxf(v, -ly[s][2]), ly[s][2]);
                v = fmaf(SIGc, ubre     - ub[s][3], q[s][3]); q[s][3] = fminf(fmaxf(v, -ly[s][3]), ly[s][3]);

                *(float4*)&s_p[r + 1][col0] = make_float4(p[s][0], p[s][1], p[s][2], p[s][3]);
                s_qe[r][cg[s] + 1] = q[s][3];
            }
            __syncthreads();

            #pragma unroll
            for (int s = 0; s < 2; ++s) {
                if (!act[s]) continue;
                const int r = rr[s], col0 = c0[s];
                float4 pup = *(const float4*)&s_p[r][col0];
                float  qe  = s_qe[r][cg[s]];

                float pu[4] = {pup.x, pup.y, pup.z, pup.w};
                float ql[4] = {qe, q[s][0], q[s][1], q[s][2]};
                #pragma unroll
                for (int e = 0; e < 4; ++e) {
                    float dv = (pu[e] - p[s][e]) + (ql[e] - q[s][e]);
                    float un = fmaf(Ac_, u[s][e], bf[s][e]);
                    un = fmaf(-Bq_, dv, un);
                    float ubn = 2.f * un - u[s][e];
                    u[s][e] = un; ub[s][e] = ubn;
                }
                *(float4*)&s_ub[r + 1][col0] = make_float4(ub[s][0], ub[s][1], ub[s][2], ub[s][3]);
            }
            __syncthreads();
        }

        if (ph == NPHASE - 1) break;
        const int par = ph & 1;

        // ---- publish interior FRAME (what any neighbor's halo can see) ----
        #pragma unroll
        for (int s = 0; s < 2; ++s) {
            if (!frame[s]) continue;
            const int idx = boff + ((gi0 + rr[s]) << 8) + (gj0 + c0[s]);
            *(float4*)&Gu [par][idx] = make_float4(u[s][0],  u[s][1],  u[s][2],  u[s][3]);
            *(float4*)&Gub[par][idx] = make_float4(ub[s][0], ub[s][1], ub[s][2], ub[s][3]);
            *(float4*)&Gp [par][idx] = make_float4(p[s][0],  p[s][1],  p[s][2],  p[s][3]);
            *(float4*)&Gq [par][idx] = make_float4(q[s][0],  q[s][1],  q[s][2],  q[s][3]);
        }
        __threadfence();                   // release: make stores agent-visible
        __syncthreads();
        if (t == 0)
            __hip_atomic_store(&flags[myfidx], ph + 1,
                               __ATOMIC_RELEASE, __HIP_MEMORY_SCOPE_AGENT);
        if (nbr >= 0)
            while (__hip_atomic_load(&flags[nfidx],
                                     __ATOMIC_ACQUIRE, __HIP_MEMORY_SCOPE_AGENT) < ph + 1) {}
        __syncthreads();
        __threadfence();                   // acquire: invalidate stale cache

        // ---- reload halo groups from neighbor frames ----
        #pragma unroll
        for (int s = 0; s < 2; ++s) {
            if (!act[s] || intr[s]) continue;
            const int gi = gi0 + rr[s], gj = gj0 + c0[s];
            float2 a0, a1;
            a0 = gld2(Gu[par] + boff, gi, gj);  a1 = gld2(Gu[par] + boff, gi, gj + 2);
            u[s][0] = a0.x; u[s][1] = a0.y; u[s][2] = a1.x; u[s][3] = a1.y;
            a0 = gld2(Gub[par] + boff, gi, gj); a1 = gld2(Gub[par] + boff, gi, gj + 2);
            ub[s][0] = a0.x; ub[s][1] = a0.y; ub[s][2] = a1.x; ub[s][3] = a1.y;
            a0 = gld2(Gp[par] + boff, gi, gj);  a1 = gld2(Gp[par] + boff, gi, gj + 2);
            p[s][0] = a0.x; p[s][1] = a0.y; p[s][2] = a1.x; p[s][3] = a1.y;
            a0 = gld2(Gq[par] + boff, gi, gj);  a1 = gld2(Gq[par] + boff, gi, gj + 2);
            q[s][0] = a0.x; q[s][1] = a0.y; q[s][2] = a1.x; q[s][3] = a1.y;

            *(float4*)&s_ub[rr[s] + 1][c0[s]] = make_float4(ub[s][0], ub[s][1], ub[s][2], ub[s][3]);
            *(float4*)&s_p [rr[s] + 1][c0[s]] = make_float4(p[s][0], p[s][1], p[s][2], p[s][3]);
            s_qe[rr[s]][cg[s] + 1] = q[s][3];
        }
        __syncthreads();
    }

    // ---------------- final store: interior u -> out ----------------
    #pragma unroll
    for (int s = 0; s < 2; ++s) {
        if (!intr[s]) continue;
        const int idx = boff + ((gi0 + rr[s]) << 8) + (gj0 + c0[s]);
        *(float4*)&out[idx] = make_float4(u[s][0], u[s][1], u[s][2], u[s][3]);
    }
}

extern "C" void kernel_launch(void* const* d_in, const int* in_sizes, int n_in,
                              void* d_out, int out_size, void* d_ws, size_t ws_size,
                              hipStream_t stream)
{
    const float* f   = (const float*)d_in[0];
    const float* lam = (const float*)d_in[1];

    tv_persist<<<dim3(256), dim3(BLK), 0, stream>>>(
        f, lam, (float*)d_out, (float*)d_ws);
}

// Round 5
// 506.968 us; speedup vs baseline: 5.4478x; 5.4478x over previous
//
#include <hip/hip_runtime.h>

// Chambolle-Pock anisotropic TV prox. B=8, H=W=256, 200 iters, fp32.
//
// Round 5: back to the relaunch scheme (round 3, 363 us) — round 4 proved
// persistent+agent-scope sync forces all exchange through HBM (125 MB
// writes + 156 MB fetches = the publish/reload, 118 us/phase).
// Two changes vs round 3:
//  (1) single barrier per iteration: only ubar lives in LDS
//      (double-buffered). p_up (row above) and q_le (col left) are
//      maintained in REGISTERS by redundant recompute — identical fp ops
//      on identical inputs as the owning thread, so values match exactly.
//      LDS ops/group-iter 7 -> 5, barriers/iter 2 -> 1, no s_p/s_qe.
//  (2) 2 blocks/CU: 512 blocks x 320 threads, interior 32x32, halo 8,
//      region 48x48 (redundancy 2.25x) so a second resident block hides
//      LDS/barrier latency. No intra-launch inter-block deps -> safe.
// Boundary semantics (verified in round 3): out-of-image lam loads give 0
// => p,q clamp to 0; explicit zeroing of the SHIFTED bounds at the pad
// rows/cols (p[-1] pad: ldn when gi<0, ldu when gi<=0; q[:,-1] pad:
// ly[e] when gj+e<0, lyle when gj<=0). Unwritten LDS edge cells produce
// garbage that advances 1 cell/iter and exactly reaches (never enters)
// the interior after 8 iters; clip via fminf/fmaxf scrubs NaN.

#define Hc 256
#define Wc 256
#define Bc 8
#define NPIX (Bc * Hc * Wc)          // 524288

#define IROWS 32
#define ICOLS 32
#define HALO  8
#define RROWS 48
#define RCOLS 48
#define NCG   (RCOLS / 4)            // 12 col-groups per row
#define NGRP  (RROWS * NCG)          // 576 groups
#define BLK   320
#define TITER 8
#define NLAUNCH 25
#define LSTR  52                      // 208 B row stride, %16==0

constexpr float TAUc = 0.35355339f;
constexpr float SIGc = 0.35355339f;
constexpr float Ac_  = 1.0f / (1.0f + TAUc);
constexpr float Bq_  = TAUc * Ac_;

__device__ __forceinline__ float2 gld2(const float* p, int gi, int gj) {
    if ((unsigned)gi < (unsigned)Hc && (unsigned)gj < (unsigned)Wc)
        return *(const float2*)(p + (gi << 8) + gj);
    return make_float2(0.f, 0.f);
}
__device__ __forceinline__ float gld1(const float* p, int gi, int gj) {
    if ((unsigned)gi < (unsigned)Hc && (unsigned)gj < (unsigned)Wc)
        return p[(gi << 8) + gj];
    return 0.f;
}
__device__ __forceinline__ float clipf(float v, float b) {
    return fminf(fmaxf(v, -b), b);
}

template <bool FIRST, bool LAST>
__global__ __launch_bounds__(BLK)
void tv_tile(const float* __restrict__ f, const float* __restrict__ lam,
             const float* __restrict__ u_in, const float* __restrict__ ub_in,
             const float* __restrict__ p_in, const float* __restrict__ q_in,
             float* __restrict__ u_out, float* __restrict__ ub_out,
             float* __restrict__ p_out, float* __restrict__ q_out)
{
    __shared__ float s_ub[2][RROWS + 2][LSTR];   // ubar only, double-buffered

    const int t   = threadIdx.x;
    const int blk = blockIdx.x;            // 0..511
    const int b   = blk >> 6;              // batch
    const int rem = blk & 63;
    const int ti  = rem >> 3;              // 0..7
    const int tj  = rem & 7;               // 0..7
    const int gi0 = ti * IROWS - HALO;
    const int gj0 = tj * ICOLS - HALO;
    const int boff = b * (Hc * Wc);

    const float* fb = f   + boff;
    const float* lb = lam + boff;

    float u[2][4], bf[2][4], ub[2][4], p[2][4], q[2][4];
    float ldn[2][4], ldu[2][4], ly[2][4], pu[2][4];
    float qle[2], lyle[2];
    int   rr[2], cg[2], c0[2];
    bool  act[2];

    // ---------------- load phase ----------------
    #pragma unroll
    for (int s = 0; s < 2; ++s) {
        const int gid = t + s * BLK;
        act[s] = (gid < NGRP);
        const int row = gid / NCG;
        const int cgv = gid - row * NCG;
        rr[s] = row; cg[s] = cgv; c0[s] = cgv * 4;
        if (!act[s]) continue;

        const int gi = gi0 + row;
        const int gj = gj0 + c0[s];

        float2 a0 = gld2(fb, gi, gj), a1 = gld2(fb, gi, gj + 2);
        const float fv0 = a0.x, fv1 = a0.y, fv2 = a1.x, fv3 = a1.y;
        bf[s][0] = Bq_ * fv0; bf[s][1] = Bq_ * fv1;
        bf[s][2] = Bq_ * fv2; bf[s][3] = Bq_ * fv3;

        // lam own row: lamr[e] = lam[gi][gj+e], e=0..4
        a0 = gld2(lb, gi, gj); a1 = gld2(lb, gi, gj + 2);
        const float le = gld1(lb, gi, gj + 4);
        ldu[s][0] = a0.x; ldu[s][1] = a0.y; ldu[s][2] = a1.x; ldu[s][3] = a1.y;
        ly[s][0]  = a0.y; ly[s][1]  = a1.x; ly[s][2]  = a1.y; ly[s][3]  = le;
        lyle[s]   = a0.x;
        // lam row below (bounds for own p): lam[gi+1][gj+e]
        a0 = gld2(lb, gi + 1, gj); a1 = gld2(lb, gi + 1, gj + 2);
        ldn[s][0] = a0.x; ldn[s][1] = a0.y; ldn[s][2] = a1.x; ldn[s][3] = a1.y;

        // pad fixes (reference: p[-1,:]=0, q[:,-1]=0; shifted bounds are
        // in-image at the pad, so zero them explicitly):
        if (gi < 0)  { ldn[s][0] = ldn[s][1] = ldn[s][2] = ldn[s][3] = 0.f; }
        if (gi <= 0) { ldu[s][0] = ldu[s][1] = ldu[s][2] = ldu[s][3] = 0.f; }
        #pragma unroll
        for (int e = 0; e < 4; ++e) if (gj + e < 0) ly[s][e] = 0.f;
        if (gj <= 0) lyle[s] = 0.f;

        if (FIRST) {
            u[s][0] = ub[s][0] = fv0; u[s][1] = ub[s][1] = fv1;
            u[s][2] = ub[s][2] = fv2; u[s][3] = ub[s][3] = fv3;
            p[s][0] = p[s][1] = p[s][2] = p[s][3] = 0.f;
            q[s][0] = q[s][1] = q[s][2] = q[s][3] = 0.f;
            pu[s][0] = pu[s][1] = pu[s][2] = pu[s][3] = 0.f;
            qle[s] = 0.f;
        } else {
            a0 = gld2(u_in + boff, gi, gj);  a1 = gld2(u_in + boff, gi, gj + 2);
            u[s][0] = a0.x; u[s][1] = a0.y; u[s][2] = a1.x; u[s][3] = a1.y;
            a0 = gld2(ub_in + boff, gi, gj); a1 = gld2(ub_in + boff, gi, gj + 2);
            ub[s][0] = a0.x; ub[s][1] = a0.y; ub[s][2] = a1.x; ub[s][3] = a1.y;
            a0 = gld2(p_in + boff, gi, gj);  a1 = gld2(p_in + boff, gi, gj + 2);
            p[s][0] = a0.x; p[s][1] = a0.y; p[s][2] = a1.x; p[s][3] = a1.y;
            a0 = gld2(q_in + boff, gi, gj);  a1 = gld2(q_in + boff, gi, gj + 2);
            q[s][0] = a0.x; q[s][1] = a0.y; q[s][2] = a1.x; q[s][3] = a1.y;
            // register copies of neighbor-owned cells
            a0 = gld2(p_in + boff, gi - 1, gj); a1 = gld2(p_in + boff, gi - 1, gj + 2);
            pu[s][0] = a0.x; pu[s][1] = a0.y; pu[s][2] = a1.x; pu[s][3] = a1.y;
            qle[s] = gld1(q_in + boff, gi, gj - 1);
        }

        *(float4*)&s_ub[0][row + 1][c0[s]] =
            make_float4(ub[s][0], ub[s][1], ub[s][2], ub[s][3]);
    }
    __syncthreads();

    // ---------------- 8 fused iterations, 1 barrier each ----------------
    #pragma unroll
    for (int k = 0; k < TITER; ++k) {
        const int cur = k & 1, nxt = cur ^ 1;
        #pragma unroll
        for (int s = 0; s < 2; ++s) {
            if (!act[s]) continue;
            const int r = rr[s], col0 = c0[s];
            const float4 ubdn = *(const float4*)&s_ub[cur][r + 2][col0];
            const float4 ubup = *(const float4*)&s_ub[cur][r][col0];
            const float  ubre = s_ub[cur][r + 1][col0 + 4];
            const float  uble = s_ub[cur][r + 1][col0 - 1];

            // own p (bounds lam[gi+1])
            p[s][0] = clipf(fmaf(SIGc, ubdn.x - ub[s][0], p[s][0]), ldn[s][0]);
            p[s][1] = clipf(fmaf(SIGc, ubdn.y - ub[s][1], p[s][1]), ldn[s][1]);
            p[s][2] = clipf(fmaf(SIGc, ubdn.z - ub[s][2], p[s][2]), ldn[s][2]);
            p[s][3] = clipf(fmaf(SIGc, ubdn.w - ub[s][3], p[s][3]), ldn[s][3]);
            // p of row above, redundant recompute (bounds lam[gi])
            pu[s][0] = clipf(fmaf(SIGc, ub[s][0] - ubup.x, pu[s][0]), ldu[s][0]);
            pu[s][1] = clipf(fmaf(SIGc, ub[s][1] - ubup.y, pu[s][1]), ldu[s][1]);
            pu[s][2] = clipf(fmaf(SIGc, ub[s][2] - ubup.z, pu[s][2]), ldu[s][2]);
            pu[s][3] = clipf(fmaf(SIGc, ub[s][3] - ubup.w, pu[s][3]), ldu[s][3]);
            // own q (bounds lam[gj+e+1])
            q[s][0] = clipf(fmaf(SIGc, ub[s][1] - ub[s][0], q[s][0]), ly[s][0]);
            q[s][1] = clipf(fmaf(SIGc, ub[s][2] - ub[s][1], q[s][1]), ly[s][1]);
            q[s][2] = clipf(fmaf(SIGc, ub[s][3] - ub[s][2], q[s][2]), ly[s][2]);
            q[s][3] = clipf(fmaf(SIGc, ubre     - ub[s][3], q[s][3]), ly[s][3]);
            // q of col left, redundant recompute (bounds lam[gj])
            qle[s] = clipf(fmaf(SIGc, ub[s][0] - uble, qle[s]), lyle[s]);

            const float ql0 = qle[s], ql1 = q[s][0], ql2 = q[s][1], ql3 = q[s][2];
            float dv, un;
            dv = (pu[s][0] - p[s][0]) + (ql0 - q[s][0]);
            un = fmaf(-Bq_, dv, fmaf(Ac_, u[s][0], bf[s][0]));
            ub[s][0] = 2.f * un - u[s][0]; u[s][0] = un;
            dv = (pu[s][1] - p[s][1]) + (ql1 - q[s][1]);
            un = fmaf(-Bq_, dv, fmaf(Ac_, u[s][1], bf[s][1]));
            ub[s][1] = 2.f * un - u[s][1]; u[s][1] = un;
            dv = (pu[s][2] - p[s][2]) + (ql2 - q[s][2]);
            un = fmaf(-Bq_, dv, fmaf(Ac_, u[s][2], bf[s][2]));
            ub[s][2] = 2.f * un - u[s][2]; u[s][2] = un;
            dv = (pu[s][3] - p[s][3]) + (ql3 - q[s][3]);
            un = fmaf(-Bq_, dv, fmaf(Ac_, u[s][3], bf[s][3]));
            ub[s][3] = 2.f * un - u[s][3]; u[s][3] = un;

            *(float4*)&s_ub[nxt][r + 1][col0] =
                make_float4(ub[s][0], ub[s][1], ub[s][2], ub[s][3]);
        }
        __syncthreads();
    }

    // ---------------- store phase (interior only) ----------------
    #pragma unroll
    for (int s = 0; s < 2; ++s) {
        if (!act[s]) continue;
        const int ir  = rr[s] - HALO;
        const int icg = cg[s] - 2;
        if ((unsigned)ir >= (unsigned)IROWS || (unsigned)icg >= 8u) continue;
        const int idx = boff + ((gi0 + rr[s]) << 8) + (gj0 + c0[s]);
        if (LAST) {
            *(float4*)&u_out[idx] = make_float4(u[s][0], u[s][1], u[s][2], u[s][3]);
        } else {
            *(float4*)&u_out [idx] = make_float4(u[s][0],  u[s][1],  u[s][2],  u[s][3]);
            *(float4*)&ub_out[idx] = make_float4(ub[s][0], ub[s][1], ub[s][2], ub[s][3]);
            *(float4*)&p_out [idx] = make_float4(p[s][0],  p[s][1],  p[s][2],  p[s][3]);
            *(float4*)&q_out [idx] = make_float4(q[s][0],  q[s][1],  q[s][2],  q[s][3]);
        }
    }
}

extern "C" void kernel_launch(void* const* d_in, const int* in_sizes, int n_in,
                              void* d_out, int out_size, void* d_ws, size_t ws_size,
                              hipStream_t stream)
{
    const float* f   = (const float*)d_in[0];
    const float* lam = (const float*)d_in[1];
    float* ws = (float*)d_ws;

    float* U [2] = { ws + 0 * (size_t)NPIX, ws + 4 * (size_t)NPIX };
    float* UB[2] = { ws + 1 * (size_t)NPIX, ws + 5 * (size_t)NPIX };
    float* P [2] = { ws + 2 * (size_t)NPIX, ws + 6 * (size_t)NPIX };
    float* Q [2] = { ws + 3 * (size_t)NPIX, ws + 7 * (size_t)NPIX };

    dim3 grid(512), block(BLK);

    tv_tile<true, false><<<grid, block, 0, stream>>>(
        f, lam, nullptr, nullptr, nullptr, nullptr,
        U[0], UB[0], P[0], Q[0]);

    for (int l = 1; l < NLAUNCH - 1; ++l) {
        const int w = l & 1, r = w ^ 1;
        tv_tile<false, false><<<grid, block, 0, stream>>>(
            f, lam, U[r], UB[r], P[r], Q[r],
            U[w], UB[w], P[w], Q[w]);
    }

    const int rlast = (NLAUNCH - 2) & 1;   // set written by launch 23
    tv_tile<false, true><<<grid, block, 0, stream>>>(
        f, lam, U[rlast], UB[rlast], P[rlast], Q[rlast],
        (float*)d_out, nullptr, nullptr, nullptr);
}

// Round 6
// 348.773 us; speedup vs baseline: 7.9187x; 1.4536x over previous
//
#include <hip/hip_runtime.h>

// Chambolle-Pock anisotropic TV prox. B=8, H=W=256, 200 iters, fp32.
//
// Round 6: round-3 geometry (interior 32x64, halo 8, region 48x80, T=8,
// 25 launches, grid 256 = 1 block/CU), new inner loop:
//  - thread owns a 2x4 patch: 24 row-pairs x 20 col-groups = 480 active
//    threads (BLK 512). Intra-pair vertical deps are in registers.
//  - only ubar in LDS (double-buffered s_ub) -> 4xb128 + 4xb32 LDS ops
//    per 8 px per iter (round 3: 4xb128+3xb32 per 4 px), 1 barrier/iter.
//  - thin ghosts by redundant recompute: 1 ghost p-row (above) + 1 ghost
//    q-col (left) per thread. Ghost inputs are the same published s_ub
//    values the owning thread uses -> bitwise-identical results.
// Boundary semantics (round-3-verified): out-of-image lam loads give 0 =>
// p,q clamp to 0. Explicit zeroing of SHIFTED bounds at the zero-pad
// rows/cols: p row i==-1 -> bound lam[0] in-image (zero bp when gi<0 /
// gi+1<0 / ghost gi-1<0); q col j==-1 likewise (bq when gj+e<0, bqg when
// gj-1<0). LDS garbage from region edges advances 1 cell/iter, reaches
// (never enters) the interior after 8 iters; clipf scrubs NaN (fminf/
// fmaxf return the non-NaN operand).

#define Hc 256
#define Wc 256
#define Bc 8
#define NPIX (Bc * Hc * Wc)          // 524288

#define IROWS 32
#define ICOLS 64
#define HALO  8
#define RROWS 48
#define RCOLS 80
#define NCG   20                      // col groups per row
#define RPAIR 24                      // row pairs
#define NACT  (RPAIR * NCG)           // 480 active threads
#define BLK   512
#define TITER 8
#define NLAUNCH 25
#define LSTR  84                      // 336 B row stride

constexpr float TAUc = 0.35355339f;
constexpr float SIGc = 0.35355339f;
constexpr float Ac_  = 1.0f / (1.0f + TAUc);
constexpr float Bq_  = TAUc * Ac_;

__device__ __forceinline__ float2 gld2(const float* p, int gi, int gj) {
    if ((unsigned)gi < (unsigned)Hc && (unsigned)gj < (unsigned)Wc)
        return *(const float2*)(p + (gi << 8) + gj);
    return make_float2(0.f, 0.f);
}
__device__ __forceinline__ float gld1(const float* p, int gi, int gj) {
    if ((unsigned)gi < (unsigned)Hc && (unsigned)gj < (unsigned)Wc)
        return p[(gi << 8) + gj];
    return 0.f;
}
__device__ __forceinline__ float clipf(float v, float b) {
    return fminf(fmaxf(v, -b), b);
}

template <bool FIRST, bool LAST>
__global__ __launch_bounds__(BLK)
void tv_tile(const float* __restrict__ f, const float* __restrict__ lam,
             const float* __restrict__ u_in, const float* __restrict__ ub_in,
             const float* __restrict__ p_in, const float* __restrict__ q_in,
             float* __restrict__ u_out, float* __restrict__ ub_out,
             float* __restrict__ p_out, float* __restrict__ q_out)
{
    // region row x lives at s_ub[.][x+1][.]  (x in -1..48 -> 0..49)
    __shared__ float s_ub[2][RROWS + 2][LSTR];

    const int t   = threadIdx.x;
    const int blk = blockIdx.x;            // 0..255
    const int b   = blk >> 5;
    const int rem = blk & 31;
    const int ti  = rem >> 2;              // 0..7
    const int tj  = rem & 3;               // 0..3
    const int gi0 = ti * IROWS - HALO;
    const int gj0 = tj * ICOLS - HALO;
    const int boff = b * (Hc * Wc);

    const bool active = (t < NACT);
    const int rp  = t / NCG;
    const int cgv = t - rp * NCG;
    const int r   = rp * 2;                // region row of top row
    const int c0  = cgv * 4;
    const int gi  = gi0 + r;               // global row of top row
    const int gj  = gj0 + c0;

    const float* fb = f + boff;
    const float* lb = lam + boff;

    float u[2][4], ub[2][4], p[2][4], q[2][4], bf[2][4];
    float pg[4], qg[2];                    // ghost p row (gi-1), ghost q col (gj-1)
    float bp[2][4], bpg[4], bq[2][4], bqg[2];

    // ---------------- load phase ----------------
    if (active) {
        float2 a0, a1;
        // f rows gi, gi+1
        a0 = gld2(fb, gi, gj); a1 = gld2(fb, gi, gj + 2);
        float fv00 = a0.x, fv01 = a0.y, fv02 = a1.x, fv03 = a1.y;
        a0 = gld2(fb, gi + 1, gj); a1 = gld2(fb, gi + 1, gj + 2);
        float fv10 = a0.x, fv11 = a0.y, fv12 = a1.x, fv13 = a1.y;
        bf[0][0] = Bq_ * fv00; bf[0][1] = Bq_ * fv01; bf[0][2] = Bq_ * fv02; bf[0][3] = Bq_ * fv03;
        bf[1][0] = Bq_ * fv10; bf[1][1] = Bq_ * fv11; bf[1][2] = Bq_ * fv12; bf[1][3] = Bq_ * fv13;

        // lam row gi: cols gj..gj+4
        a0 = gld2(lb, gi, gj); a1 = gld2(lb, gi, gj + 2);
        float l04 = gld1(lb, gi, gj + 4);
        bpg[0] = a0.x; bpg[1] = a0.y; bpg[2] = a1.x; bpg[3] = a1.y;  // ghost p bound = lam[gi]
        bq[0][0] = a0.y; bq[0][1] = a1.x; bq[0][2] = a1.y; bq[0][3] = l04;
        bqg[0] = a0.x;                                               // ghost q bound = lam[gi][gj]
        // lam row gi+1
        a0 = gld2(lb, gi + 1, gj); a1 = gld2(lb, gi + 1, gj + 2);
        float l14 = gld1(lb, gi + 1, gj + 4);
        bp[0][0] = a0.x; bp[0][1] = a0.y; bp[0][2] = a1.x; bp[0][3] = a1.y; // p row gi bound = lam[gi+1]
        bq[1][0] = a0.y; bq[1][1] = a1.x; bq[1][2] = a1.y; bq[1][3] = l14;
        bqg[1] = a0.x;
        // lam row gi+2
        a0 = gld2(lb, gi + 2, gj); a1 = gld2(lb, gi + 2, gj + 2);
        bp[1][0] = a0.x; bp[1][1] = a0.y; bp[1][2] = a1.x; bp[1][3] = a1.y; // p row gi+1 bound

        // pad fixes: p at global row -1 == 0, q at global col -1 == 0;
        // their shifted bounds are in-image there -> zero explicitly.
        if (gi     < 0) { bp[0][0] = bp[0][1] = bp[0][2] = bp[0][3] = 0.f; }
        if (gi + 1 < 0) { bp[1][0] = bp[1][1] = bp[1][2] = bp[1][3] = 0.f; }
        if (gi - 1 < 0) { bpg[0] = bpg[1] = bpg[2] = bpg[3] = 0.f; }
        #pragma unroll
        for (int e = 0; e < 4; ++e)
            if (gj + e < 0) { bq[0][e] = 0.f; bq[1][e] = 0.f; }
        if (gj - 1 < 0) { bqg[0] = 0.f; bqg[1] = 0.f; }

        if (FIRST) {
            u[0][0] = ub[0][0] = fv00; u[0][1] = ub[0][1] = fv01;
            u[0][2] = ub[0][2] = fv02; u[0][3] = ub[0][3] = fv03;
            u[1][0] = ub[1][0] = fv10; u[1][1] = ub[1][1] = fv11;
            u[1][2] = ub[1][2] = fv12; u[1][3] = ub[1][3] = fv13;
            #pragma unroll
            for (int e = 0; e < 4; ++e) { p[0][e] = p[1][e] = q[0][e] = q[1][e] = pg[e] = 0.f; }
            qg[0] = qg[1] = 0.f;
        } else {
            #pragma unroll
            for (int row = 0; row < 2; ++row) {
                a0 = gld2(u_in + boff, gi + row, gj);  a1 = gld2(u_in + boff, gi + row, gj + 2);
                u[row][0] = a0.x; u[row][1] = a0.y; u[row][2] = a1.x; u[row][3] = a1.y;
                a0 = gld2(ub_in + boff, gi + row, gj); a1 = gld2(ub_in + boff, gi + row, gj + 2);
                ub[row][0] = a0.x; ub[row][1] = a0.y; ub[row][2] = a1.x; ub[row][3] = a1.y;
                a0 = gld2(p_in + boff, gi + row, gj);  a1 = gld2(p_in + boff, gi + row, gj + 2);
                p[row][0] = a0.x; p[row][1] = a0.y; p[row][2] = a1.x; p[row][3] = a1.y;
                a0 = gld2(q_in + boff, gi + row, gj);  a1 = gld2(q_in + boff, gi + row, gj + 2);
                q[row][0] = a0.x; q[row][1] = a0.y; q[row][2] = a1.x; q[row][3] = a1.y;
            }
            a0 = gld2(p_in + boff, gi - 1, gj); a1 = gld2(p_in + boff, gi - 1, gj + 2);
            pg[0] = a0.x; pg[1] = a0.y; pg[2] = a1.x; pg[3] = a1.y;
            qg[0] = gld1(q_in + boff, gi,     gj - 1);
            qg[1] = gld1(q_in + boff, gi + 1, gj - 1);
        }

        *(float4*)&s_ub[0][r + 1][c0] = make_float4(ub[0][0], ub[0][1], ub[0][2], ub[0][3]);
        *(float4*)&s_ub[0][r + 2][c0] = make_float4(ub[1][0], ub[1][1], ub[1][2], ub[1][3]);
    }
    __syncthreads();

    // ---------------- 8 fused iterations, 1 barrier each ----------------
    #pragma unroll
    for (int k = 0; k < TITER; ++k) {
        const int cur = k & 1, nxt = cur ^ 1;
        if (active) {
            const float4 ubm1 = *(const float4*)&s_ub[cur][r][c0];      // row r-1
            const float4 ubp2 = *(const float4*)&s_ub[cur][r + 3][c0];  // row r+2
            const float  ubre0 = s_ub[cur][r + 1][c0 + 4];
            const float  ubre1 = s_ub[cur][r + 2][c0 + 4];
            const float  uble0 = s_ub[cur][r + 1][c0 - 1];              // c0-1>=-1: in alloc, halo-safe
            const float  uble1 = s_ub[cur][r + 2][c0 - 1];

            // ---- step 1: p, q, ghosts (all from prev-iter ubar) ----
            pg[0] = clipf(fmaf(SIGc, ub[0][0] - ubm1.x, pg[0]), bpg[0]);
            pg[1] = clipf(fmaf(SIGc, ub[0][1] - ubm1.y, pg[1]), bpg[1]);
            pg[2] = clipf(fmaf(SIGc, ub[0][2] - ubm1.z, pg[2]), bpg[2]);
            pg[3] = clipf(fmaf(SIGc, ub[0][3] - ubm1.w, pg[3]), bpg[3]);

            p[0][0] = clipf(fmaf(SIGc, ub[1][0] - ub[0][0], p[0][0]), bp[0][0]);
            p[0][1] = clipf(fmaf(SIGc, ub[1][1] - ub[0][1], p[0][1]), bp[0][1]);
            p[0][2] = clipf(fmaf(SIGc, ub[1][2] - ub[0][2], p[0][2]), bp[0][2]);
            p[0][3] = clipf(fmaf(SIGc, ub[1][3] - ub[0][3], p[0][3]), bp[0][3]);

            p[1][0] = clipf(fmaf(SIGc, ubp2.x - ub[1][0], p[1][0]), bp[1][0]);
            p[1][1] = clipf(fmaf(SIGc, ubp2.y - ub[1][1], p[1][1]), bp[1][1]);
            p[1][2] = clipf(fmaf(SIGc, ubp2.z - ub[1][2], p[1][2]), bp[1][2]);
            p[1][3] = clipf(fmaf(SIGc, ubp2.w - ub[1][3], p[1][3]), bp[1][3]);

            qg[0] = clipf(fmaf(SIGc, ub[0][0] - uble0, qg[0]), bqg[0]);
            qg[1] = clipf(fmaf(SIGc, ub[1][0] - uble1, qg[1]), bqg[1]);

            q[0][0] = clipf(fmaf(SIGc, ub[0][1] - ub[0][0], q[0][0]), bq[0][0]);
            q[0][1] = clipf(fmaf(SIGc, ub[0][2] - ub[0][1], q[0][1]), bq[0][1]);
            q[0][2] = clipf(fmaf(SIGc, ub[0][3] - ub[0][2], q[0][2]), bq[0][2]);
            q[0][3] = clipf(fmaf(SIGc, ubre0    - ub[0][3], q[0][3]), bq[0][3]);

            q[1][0] = clipf(fmaf(SIGc, ub[1][1] - ub[1][0], q[1][0]), bq[1][0]);
            q[1][1] = clipf(fmaf(SIGc, ub[1][2] - ub[1][1], q[1][1]), bq[1][1]);
            q[1][2] = clipf(fmaf(SIGc, ub[1][3] - ub[1][2], q[1][2]), bq[1][2]);
            q[1][3] = clipf(fmaf(SIGc, ubre1    - ub[1][3], q[1][3]), bq[1][3]);

            // ---- step 2: u, ubar (no barrier: cross-thread inputs are ghosts/own) ----
            float dv, un;
            // row 0: p_up = ghost, q_left = {qg[0], q[0][0..2]}
            dv = (pg[0] - p[0][0]) + (qg[0]   - q[0][0]);
            un = fmaf(-Bq_, dv, fmaf(Ac_, u[0][0], bf[0][0]));
            ub[0][0] = 2.f * un - u[0][0]; u[0][0] = un;
            dv = (pg[1] - p[0][1]) + (q[0][0] - q[0][1]);
            un = fmaf(-Bq_, dv, fmaf(Ac_, u[0][1], bf[0][1]));
            ub[0][1] = 2.f * un - u[0][1]; u[0][1] = un;
            dv = (pg[2] - p[0][2]) + (q[0][1] - q[0][2]);
            un = fmaf(-Bq_, dv, fmaf(Ac_, u[0][2], bf[0][2]));
            ub[0][2] = 2.f * un - u[0][2]; u[0][2] = un;
            dv = (pg[3] - p[0][3]) + (q[0][2] - q[0][3]);
            un = fmaf(-Bq_, dv, fmaf(Ac_, u[0][3], bf[0][3]));
            ub[0][3] = 2.f * un - u[0][3]; u[0][3] = un;
            // row 1: p_up = p[0] (regs), q_left = {qg[1], q[1][0..2]}
            dv = (p[0][0] - p[1][0]) + (qg[1]   - q[1][0]);
            un = fmaf(-Bq_, dv, fmaf(Ac_, u[1][0], bf[1][0]));
            ub[1][0] = 2.f * un - u[1][0]; u[1][0] = un;
            dv = (p[0][1] - p[1][1]) + (q[1][0] - q[1][1]);
            un = fmaf(-Bq_, dv, fmaf(Ac_, u[1][1], bf[1][1]));
            ub[1][1] = 2.f * un - u[1][1]; u[1][1] = un;
            dv = (p[0][2] - p[1][2]) + (q[1][1] - q[1][2]);
            un = fmaf(-Bq_, dv, fmaf(Ac_, u[1][2], bf[1][2]));
            ub[1][2] = 2.f * un - u[1][2]; u[1][2] = un;
            dv = (p[0][3] - p[1][3]) + (q[1][2] - q[1][3]);
            un = fmaf(-Bq_, dv, fmaf(Ac_, u[1][3], bf[1][3]));
            ub[1][3] = 2.f * un - u[1][3]; u[1][3] = un;

            *(float4*)&s_ub[nxt][r + 1][c0] = make_float4(ub[0][0], ub[0][1], ub[0][2], ub[0][3]);
            *(float4*)&s_ub[nxt][r + 2][c0] = make_float4(ub[1][0], ub[1][1], ub[1][2], ub[1][3]);
        }
        __syncthreads();
    }

    // ---------------- store phase (interior only) ----------------
    if (active && r >= HALO && r < HALO + IROWS && cgv >= 2 && cgv < 18) {
        const int idx0 = boff + (gi << 8) + gj;
        const int idx1 = idx0 + Wc;
        if (LAST) {
            *(float4*)&u_out[idx0] = make_float4(u[0][0], u[0][1], u[0][2], u[0][3]);
            *(float4*)&u_out[idx1] = make_float4(u[1][0], u[1][1], u[1][2], u[1][3]);
        } else {
            *(float4*)&u_out [idx0] = make_float4(u[0][0],  u[0][1],  u[0][2],  u[0][3]);
            *(float4*)&u_out [idx1] = make_float4(u[1][0],  u[1][1],  u[1][2],  u[1][3]);
            *(float4*)&ub_out[idx0] = make_float4(ub[0][0], ub[0][1], ub[0][2], ub[0][3]);
            *(float4*)&ub_out[idx1] = make_float4(ub[1][0], ub[1][1], ub[1][2], ub[1][3]);
            *(float4*)&p_out [idx0] = make_float4(p[0][0],  p[0][1],  p[0][2],  p[0][3]);
            *(float4*)&p_out [idx1] = make_float4(p[1][0],  p[1][1],  p[1][2],  p[1][3]);
            *(float4*)&q_out [idx0] = make_float4(q[0][0],  q[0][1],  q[0][2],  q[0][3]);
            *(float4*)&q_out [idx1] = make_float4(q[1][0],  q[1][1],  q[1][2],  q[1][3]);
        }
    }
}

extern "C" void kernel_launch(void* const* d_in, const int* in_sizes, int n_in,
                              void* d_out, int out_size, void* d_ws, size_t ws_size,
                              hipStream_t stream)
{
    const float* f   = (const float*)d_in[0];
    const float* lam = (const float*)d_in[1];
    float* ws = (float*)d_ws;

    float* U [2] = { ws + 0 * (size_t)NPIX, ws + 4 * (size_t)NPIX };
    float* UB[2] = { ws + 1 * (size_t)NPIX, ws + 5 * (size_t)NPIX };
    float* P [2] = { ws + 2 * (size_t)NPIX, ws + 6 * (size_t)NPIX };
    float* Q [2] = { ws + 3 * (size_t)NPIX, ws + 7 * (size_t)NPIX };

    dim3 grid(256), block(BLK);

    tv_tile<true, false><<<grid, block, 0, stream>>>(
        f, lam, nullptr, nullptr, nullptr, nullptr,
        U[0], UB[0], P[0], Q[0]);

    for (int l = 1; l < NLAUNCH - 1; ++l) {
        const int w = l & 1, r = w ^ 1;
        tv_tile<false, false><<<grid, block, 0, stream>>>(
            f, lam, U[r], UB[r], P[r], Q[r],
            U[w], UB[w], P[w], Q[w]);
    }

    const int rlast = (NLAUNCH - 2) & 1;
    tv_tile<false, true><<<grid, block, 0, stream>>>(
        f, lam, U[rlast], UB[rlast], P[rlast], Q[rlast],
        (float*)d_out, nullptr, nullptr, nullptr);
}

// Round 7
// 301.612 us; speedup vs baseline: 9.1569x; 1.1564x over previous
//
#include <hip/hip_runtime.h>

// Chambolle-Pock anisotropic TV prox. B=8, H=W=256, 200 iters, fp32.
//
// Round 7: round-6 inner loop (2x4 patch/thread, ubar-only LDS dbuf,
// thin register ghosts, 1 barrier/iter), T raised 8 -> 16:
//   12 launches of T=16 (interior 32x64, halo 16, region 64x96,
//   768 threads) + 1 final launch of T=8 (round-6 geometry) = 200 iters,
//   13 launches total (was 25). Launch-count-dominated cost model:
//   N*(fixed + alpha*region) + beta*sum(region*T); T=16 trades 3.2x
//   redundant compute for halving N.
// Also: guarded float4 loads for f/state (4-px groups are 4-aligned and
// W=256 => fully in- or out-of-image; lam keeps shifted gld2/gld1).
// Boundary semantics (rounds 3/6-verified): OOB lam -> 0 -> p,q clamp 0;
// explicitly zero SHIFTED bounds at pads (p[-1]: bp/bpg when row<0;
// q[:,-1]: bq/bqg when col<0). LDS edge garbage advances 1 cell/iter,
// reaches (never enters) interior after T iters; clipf scrubs NaN.

#define Hc 256
#define Wc 256
#define Bc 8
#define NPIX (Bc * Hc * Wc)          // 524288

constexpr int RRv(int T)   { return 32 + 2 * T; }          // region rows
constexpr int RCv(int T)   { return 64 + 2 * T; }          // region cols
constexpr int NCGv(int T)  { return RCv(T) / 4; }          // col groups
constexpr int NACTv(int T) { return (RRv(T) / 2) * NCGv(T); }
constexpr int BLKv(int T)  { return (NACTv(T) + 63) / 64 * 64; }
constexpr int LSTRv(int T) { return (RCv(T) + 2 + 3) / 4 * 4; }  // 16B-mult row stride

constexpr float TAUc = 0.35355339f;
constexpr float SIGc = 0.35355339f;
constexpr float Ac_  = 1.0f / (1.0f + TAUc);
constexpr float Bq_  = TAUc * Ac_;

__device__ __forceinline__ float4 gld4(const float* p, int gi, int gj) {
    // gj is 4-aligned; group fully in-image iff 0<=gi<H and 0<=gj<W
    if ((unsigned)gi < (unsigned)Hc && (unsigned)gj < (unsigned)Wc)
        return *(const float4*)(p + (gi << 8) + gj);
    return make_float4(0.f, 0.f, 0.f, 0.f);
}
__device__ __forceinline__ float2 gld2(const float* p, int gi, int gj) {
    if ((unsigned)gi < (unsigned)Hc && (unsigned)gj < (unsigned)Wc)
        return *(const float2*)(p + (gi << 8) + gj);
    return make_float2(0.f, 0.f);
}
__device__ __forceinline__ float gld1(const float* p, int gi, int gj) {
    if ((unsigned)gi < (unsigned)Hc && (unsigned)gj < (unsigned)Wc)
        return p[(gi << 8) + gj];
    return 0.f;
}
__device__ __forceinline__ float clipf(float v, float b) {
    return fminf(fmaxf(v, -b), b);
}

template <int T, bool FIRST, bool LAST>
__global__ __launch_bounds__(BLKv(T))
void tv_tile(const float* __restrict__ f, const float* __restrict__ lam,
             const float* __restrict__ u_in, const float* __restrict__ ub_in,
             const float* __restrict__ p_in, const float* __restrict__ q_in,
             float* __restrict__ u_out, float* __restrict__ ub_out,
             float* __restrict__ p_out, float* __restrict__ q_out)
{
    constexpr int RR   = RRv(T);
    constexpr int NCG  = NCGv(T);
    constexpr int NACT = NACTv(T);
    constexpr int LSTR = LSTRv(T);

    // region row x lives at s_ub[.][x+1][.]
    __shared__ float s_ub[2][RR + 2][LSTR];

    const int t   = threadIdx.x;
    const int blk = blockIdx.x;            // 0..255
    const int b   = blk >> 5;
    const int rem = blk & 31;
    const int ti  = rem >> 2;              // 0..7
    const int tj  = rem & 3;               // 0..3
    const int gi0 = ti * 32 - T;
    const int gj0 = tj * 64 - T;
    const int boff = b * (Hc * Wc);

    const bool active = (NACT == BLKv(T)) || (t < NACT);
    const int rp  = t / NCG;
    const int cgv = t - rp * NCG;
    const int r   = rp * 2;                // region row of top row
    const int c0  = cgv * 4;
    const int gi  = gi0 + r;               // global row of top row
    const int gj  = gj0 + c0;

    const float* fb = f + boff;
    const float* lb = lam + boff;

    float u[2][4], ub[2][4], p[2][4], q[2][4], bf[2][4];
    float pg[4], qg[2];                    // ghost p row (gi-1), ghost q col (gj-1)
    float bp[2][4], bpg[4], bq[2][4], bqg[2];

    // ---------------- load phase ----------------
    if (active) {
        float4 v0, v1;
        v0 = gld4(fb, gi, gj); v1 = gld4(fb, gi + 1, gj);
        bf[0][0] = Bq_ * v0.x; bf[0][1] = Bq_ * v0.y; bf[0][2] = Bq_ * v0.z; bf[0][3] = Bq_ * v0.w;
        bf[1][0] = Bq_ * v1.x; bf[1][1] = Bq_ * v1.y; bf[1][2] = Bq_ * v1.z; bf[1][3] = Bq_ * v1.w;
        const float4 fr0 = v0, fr1 = v1;

        // lam row gi (cols gj..gj+4), row gi+1, row gi+2
        float4 l0 = gld4(lb, gi, gj);     const float l04 = gld1(lb, gi, gj + 4);
        float4 l1 = gld4(lb, gi + 1, gj); const float l14 = gld1(lb, gi + 1, gj + 4);
        float4 l2 = gld4(lb, gi + 2, gj);
        bpg[0] = l0.x; bpg[1] = l0.y; bpg[2] = l0.z; bpg[3] = l0.w;   // ghost p bound = lam[gi]
        bq[0][0] = l0.y; bq[0][1] = l0.z; bq[0][2] = l0.w; bq[0][3] = l04;
        bqg[0] = l0.x;
        bp[0][0] = l1.x; bp[0][1] = l1.y; bp[0][2] = l1.z; bp[0][3] = l1.w;  // p row gi bound
        bq[1][0] = l1.y; bq[1][1] = l1.z; bq[1][2] = l1.w; bq[1][3] = l14;
        bqg[1] = l1.x;
        bp[1][0] = l2.x; bp[1][1] = l2.y; bp[1][2] = l2.z; bp[1][3] = l2.w;  // p row gi+1 bound

        // pad fixes: p at global row -1 == 0, q at global col -1 == 0;
        // their SHIFTED bounds are in-image there -> zero explicitly.
        if (gi     < 0) { bp[0][0] = bp[0][1] = bp[0][2] = bp[0][3] = 0.f; }
        if (gi + 1 < 0) { bp[1][0] = bp[1][1] = bp[1][2] = bp[1][3] = 0.f; }
        if (gi - 1 < 0) { bpg[0] = bpg[1] = bpg[2] = bpg[3] = 0.f; }
        #pragma unroll
        for (int e = 0; e < 4; ++e)
            if (gj + e < 0) { bq[0][e] = 0.f; bq[1][e] = 0.f; }
        if (gj - 1 < 0) { bqg[0] = 0.f; bqg[1] = 0.f; }

        if (FIRST) {
            u[0][0] = ub[0][0] = fr0.x; u[0][1] = ub[0][1] = fr0.y;
            u[0][2] = ub[0][2] = fr0.z; u[0][3] = ub[0][3] = fr0.w;
            u[1][0] = ub[1][0] = fr1.x; u[1][1] = ub[1][1] = fr1.y;
            u[1][2] = ub[1][2] = fr1.z; u[1][3] = ub[1][3] = fr1.w;
            #pragma unroll
            for (int e = 0; e < 4; ++e) { p[0][e] = p[1][e] = q[0][e] = q[1][e] = pg[e] = 0.f; }
            qg[0] = qg[1] = 0.f;
        } else {
            #pragma unroll
            for (int row = 0; row < 2; ++row) {
                v0 = gld4(u_in + boff, gi + row, gj);
                u[row][0] = v0.x; u[row][1] = v0.y; u[row][2] = v0.z; u[row][3] = v0.w;
                v0 = gld4(ub_in + boff, gi + row, gj);
                ub[row][0] = v0.x; ub[row][1] = v0.y; ub[row][2] = v0.z; ub[row][3] = v0.w;
                v0 = gld4(p_in + boff, gi + row, gj);
                p[row][0] = v0.x; p[row][1] = v0.y; p[row][2] = v0.z; p[row][3] = v0.w;
                v0 = gld4(q_in + boff, gi + row, gj);
                q[row][0] = v0.x; q[row][1] = v0.y; q[row][2] = v0.z; q[row][3] = v0.w;
            }
            v0 = gld4(p_in + boff, gi - 1, gj);
            pg[0] = v0.x; pg[1] = v0.y; pg[2] = v0.z; pg[3] = v0.w;
            qg[0] = gld1(q_in + boff, gi,     gj - 1);
            qg[1] = gld1(q_in + boff, gi + 1, gj - 1);
        }

        *(float4*)&s_ub[0][r + 1][c0] = make_float4(ub[0][0], ub[0][1], ub[0][2], ub[0][3]);
        *(float4*)&s_ub[0][r + 2][c0] = make_float4(ub[1][0], ub[1][1], ub[1][2], ub[1][3]);
    }
    __syncthreads();

    // ---------------- T fused iterations, 1 barrier each ----------------
    auto iter_step = [&](int cur) {
        const int nxt = cur ^ 1;
        if (active) {
            const float4 ubm1 = *(const float4*)&s_ub[cur][r][c0];      // row r-1
            const float4 ubp2 = *(const float4*)&s_ub[cur][r + 3][c0];  // row r+2
            const float  ubre0 = s_ub[cur][r + 1][c0 + 4];
            const float  ubre1 = s_ub[cur][r + 2][c0 + 4];
            const float  uble0 = s_ub[cur][r + 1][c0 - 1];
            const float  uble1 = s_ub[cur][r + 2][c0 - 1];

            // ---- step 1: p, q, ghosts (from prev-iter ubar) ----
            pg[0] = clipf(fmaf(SIGc, ub[0][0] - ubm1.x, pg[0]), bpg[0]);
            pg[1] = clipf(fmaf(SIGc, ub[0][1] - ubm1.y, pg[1]), bpg[1]);
            pg[2] = clipf(fmaf(SIGc, ub[0][2] - ubm1.z, pg[2]), bpg[2]);
            pg[3] = clipf(fmaf(SIGc, ub[0][3] - ubm1.w, pg[3]), bpg[3]);

            p[0][0] = clipf(fmaf(SIGc, ub[1][0] - ub[0][0], p[0][0]), bp[0][0]);
            p[0][1] = clipf(fmaf(SIGc, ub[1][1] - ub[0][1], p[0][1]), bp[0][1]);
            p[0][2] = clipf(fmaf(SIGc, ub[1][2] - ub[0][2], p[0][2]), bp[0][2]);
            p[0][3] = clipf(fmaf(SIGc, ub[1][3] - ub[0][3], p[0][3]), bp[0][3]);

            p[1][0] = clipf(fmaf(SIGc, ubp2.x - ub[1][0], p[1][0]), bp[1][0]);
            p[1][1] = clipf(fmaf(SIGc, ubp2.y - ub[1][1], p[1][1]), bp[1][1]);
            p[1][2] = clipf(fmaf(SIGc, ubp2.z - ub[1][2], p[1][2]), bp[1][2]);
            p[1][3] = clipf(fmaf(SIGc, ubp2.w - ub[1][3], p[1][3]), bp[1][3]);

            qg[0] = clipf(fmaf(SIGc, ub[0][0] - uble0, qg[0]), bqg[0]);
            qg[1] = clipf(fmaf(SIGc, ub[1][0] - uble1, qg[1]), bqg[1]);

            q[0][0] = clipf(fmaf(SIGc, ub[0][1] - ub[0][0], q[0][0]), bq[0][0]);
            q[0][1] = clipf(fmaf(SIGc, ub[0][2] - ub[0][1], q[0][1]), bq[0][1]);
            q[0][2] = clipf(fmaf(SIGc, ub[0][3] - ub[0][2], q[0][2]), bq[0][2]);
            q[0][3] = clipf(fmaf(SIGc, ubre0    - ub[0][3], q[0][3]), bq[0][3]);

            q[1][0] = clipf(fmaf(SIGc, ub[1][1] - ub[1][0], q[1][0]), bq[1][0]);
            q[1][1] = clipf(fmaf(SIGc, ub[1][2] - ub[1][1], q[1][1]), bq[1][1]);
            q[1][2] = clipf(fmaf(SIGc, ub[1][3] - ub[1][2], q[1][2]), bq[1][2]);
            q[1][3] = clipf(fmaf(SIGc, ubre1    - ub[1][3], q[1][3]), bq[1][3]);

            // ---- step 2: u, ubar ----
            float dv, un;
            dv = (pg[0] - p[0][0]) + (qg[0]   - q[0][0]);
            un = fmaf(-Bq_, dv, fmaf(Ac_, u[0][0], bf[0][0]));
            ub[0][0] = 2.f * un - u[0][0]; u[0][0] = un;
            dv = (pg[1] - p[0][1]) + (q[0][0] - q[0][1]);
            un = fmaf(-Bq_, dv, fmaf(Ac_, u[0][1], bf[0][1]));
            ub[0][1] = 2.f * un - u[0][1]; u[0][1] = un;
            dv = (pg[2] - p[0][2]) + (q[0][1] - q[0][2]);
            un = fmaf(-Bq_, dv, fmaf(Ac_, u[0][2], bf[0][2]));
            ub[0][2] = 2.f * un - u[0][2]; u[0][2] = un;
            dv = (pg[3] - p[0][3]) + (q[0][2] - q[0][3]);
            un = fmaf(-Bq_, dv, fmaf(Ac_, u[0][3], bf[0][3]));
            ub[0][3] = 2.f * un - u[0][3]; u[0][3] = un;

            dv = (p[0][0] - p[1][0]) + (qg[1]   - q[1][0]);
            un = fmaf(-Bq_, dv, fmaf(Ac_, u[1][0], bf[1][0]));
            ub[1][0] = 2.f * un - u[1][0]; u[1][0] = un;
            dv = (p[0][1] - p[1][1]) + (q[1][0] - q[1][1]);
            un = fmaf(-Bq_, dv, fmaf(Ac_, u[1][1], bf[1][1]));
            ub[1][1] = 2.f * un - u[1][1]; u[1][1] = un;
            dv = (p[0][2] - p[1][2]) + (q[1][1] - q[1][2]);
            un = fmaf(-Bq_, dv, fmaf(Ac_, u[1][2], bf[1][2]));
            ub[1][2] = 2.f * un - u[1][2]; u[1][2] = un;
            dv = (p[0][3] - p[1][3]) + (q[1][2] - q[1][3]);
            un = fmaf(-Bq_, dv, fmaf(Ac_, u[1][3], bf[1][3]));
            ub[1][3] = 2.f * un - u[1][3]; u[1][3] = un;

            *(float4*)&s_ub[nxt][r + 1][c0] = make_float4(ub[0][0], ub[0][1], ub[0][2], ub[0][3]);
            *(float4*)&s_ub[nxt][r + 2][c0] = make_float4(ub[1][0], ub[1][1], ub[1][2], ub[1][3]);
        }
        __syncthreads();
    };

    for (int kk = 0; kk < T / 2; ++kk) { iter_step(0); iter_step(1); }

    // ---------------- store phase (interior only) ----------------
    if (active && r >= T && r < T + 32 && cgv >= T / 4 && cgv < T / 4 + 16) {
        const int idx0 = boff + (gi << 8) + gj;
        const int idx1 = idx0 + Wc;
        if (LAST) {
            *(float4*)&u_out[idx0] = make_float4(u[0][0], u[0][1], u[0][2], u[0][3]);
            *(float4*)&u_out[idx1] = make_float4(u[1][0], u[1][1], u[1][2], u[1][3]);
        } else {
            *(float4*)&u_out [idx0] = make_float4(u[0][0],  u[0][1],  u[0][2],  u[0][3]);
            *(float4*)&u_out [idx1] = make_float4(u[1][0],  u[1][1],  u[1][2],  u[1][3]);
            *(float4*)&ub_out[idx0] = make_float4(ub[0][0], ub[0][1], ub[0][2], ub[0][3]);
            *(float4*)&ub_out[idx1] = make_float4(ub[1][0], ub[1][1], ub[1][2], ub[1][3]);
            *(float4*)&p_out [idx0] = make_float4(p[0][0],  p[0][1],  p[0][2],  p[0][3]);
            *(float4*)&p_out [idx1] = make_float4(p[1][0],  p[1][1],  p[1][2],  p[1][3]);
            *(float4*)&q_out [idx0] = make_float4(q[0][0],  q[0][1],  q[0][2],  q[0][3]);
            *(float4*)&q_out [idx1] = make_float4(q[1][0],  q[1][1],  q[1][2],  q[1][3]);
        }
    }
}

extern "C" void kernel_launch(void* const* d_in, const int* in_sizes, int n_in,
                              void* d_out, int out_size, void* d_ws, size_t ws_size,
                              hipStream_t stream)
{
    const float* f   = (const float*)d_in[0];
    const float* lam = (const float*)d_in[1];
    float* ws = (float*)d_ws;

    float* U [2] = { ws + 0 * (size_t)NPIX, ws + 4 * (size_t)NPIX };
    float* UB[2] = { ws + 1 * (size_t)NPIX, ws + 5 * (size_t)NPIX };
    float* P [2] = { ws + 2 * (size_t)NPIX, ws + 6 * (size_t)NPIX };
    float* Q [2] = { ws + 3 * (size_t)NPIX, ws + 7 * (size_t)NPIX };

    dim3 grid(256);

    // 12 launches of T=16 (iters 0..191) + 1 launch of T=8 (iters 192..199)
    tv_tile<16, true, false><<<grid, dim3(BLKv(16)), 0, stream>>>(
        f, lam, nullptr, nullptr, nullptr, nullptr,
        U[0], UB[0], P[0], Q[0]);

    for (int l = 1; l < 12; ++l) {
        const int w = l & 1, r = w ^ 1;
        tv_tile<16, false, false><<<grid, dim3(BLKv(16)), 0, stream>>>(
            f, lam, U[r], UB[r], P[r], Q[r],
            U[w], UB[w], P[w], Q[w]);
    }

    // launch 11 wrote set 1; final T=8 launch reads set 1, writes u -> d_out
    tv_tile<8, false, true><<<grid, dim3(BLKv(8)), 0, stream>>>(
        f, lam, U[1], UB[1], P[1], Q[1],
        (float*)d_out, nullptr, nullptr, nullptr);
}

// Round 8
// 267.828 us; speedup vs baseline: 10.3120x; 1.1261x over previous
//
#include <hip/hip_runtime.h>

// Chambolle-Pock anisotropic TV prox. B=8, H=W=256, 200 iters, fp32.
//
// Round 8: round-7 structure (T=16 x12 + T=8 x1, 2x4 patch/thread,
// ubar-only LDS dbuf, register ghosts, 1 barrier/iter) with two
// instruction-level changes:
//  (1) clamp via v_med3_f32 (__builtin_amdgcn_fmed3f(v,-b,b)) — 1 inst
//      instead of fminf(fmaxf()) 2. NaN garbage -> med3 returns min of
//      the other two = -b (finite; ±0 when b==0), so the halo
//      garbage-containment proof is unchanged.
//  (2) XCD-quad block swizzle: blk%8 == XCD (heuristic, perf-only);
//      decode blk so each 2x2 tile quad lives on one XCD -> halo loads
//      between quad members are XCD-local L2 hits.
// Cost model (fit to r6/r7): total = N*9.8us + 0.33cyc*sum(region*T);
// this round attacks the work-term's VALU component.
// Boundary semantics (r3/r6-verified): OOB lam -> 0 -> p,q clamp to 0;
// explicitly zero SHIFTED bounds at pads (p[-1]: bp/bpg when row<0;
// q[:,-1]: bq/bqg when col<0). LDS edge garbage advances 1 cell/iter,
// reaches (never enters) interior after T iters.

#define Hc 256
#define Wc 256
#define Bc 8
#define NPIX (Bc * Hc * Wc)          // 524288

constexpr int RRv(int T)   { return 32 + 2 * T; }          // region rows
constexpr int RCv(int T)   { return 64 + 2 * T; }          // region cols
constexpr int NCGv(int T)  { return RCv(T) / 4; }          // col groups
constexpr int NACTv(int T) { return (RRv(T) / 2) * NCGv(T); }
constexpr int BLKv(int T)  { return (NACTv(T) + 63) / 64 * 64; }
constexpr int LSTRv(int T) { return (RCv(T) + 2 + 3) / 4 * 4; }  // 16B-mult row stride

constexpr float TAUc = 0.35355339f;
constexpr float SIGc = 0.35355339f;
constexpr float Ac_  = 1.0f / (1.0f + TAUc);
constexpr float Bq_  = TAUc * Ac_;

__device__ __forceinline__ float4 gld4(const float* p, int gi, int gj) {
    // gj is 4-aligned; group fully in-image iff 0<=gi<H and 0<=gj<W
    if ((unsigned)gi < (unsigned)Hc && (unsigned)gj < (unsigned)Wc)
        return *(const float4*)(p + (gi << 8) + gj);
    return make_float4(0.f, 0.f, 0.f, 0.f);
}
__device__ __forceinline__ float gld1(const float* p, int gi, int gj) {
    if ((unsigned)gi < (unsigned)Hc && (unsigned)gj < (unsigned)Wc)
        return p[(gi << 8) + gj];
    return 0.f;
}
// clamp to [-b, b] in one v_med3_f32 (the -b modifier is free).
// NaN v -> med3 returns min(-b, b) = -b: finite, 0 when b==0.
__device__ __forceinline__ float clipf(float v, float b) {
    return __builtin_amdgcn_fmed3f(v, -b, b);
}

template <int T, bool FIRST, bool LAST>
__global__ __launch_bounds__(BLKv(T))
void tv_tile(const float* __restrict__ f, const float* __restrict__ lam,
             const float* __restrict__ u_in, const float* __restrict__ ub_in,
             const float* __restrict__ p_in, const float* __restrict__ q_in,
             float* __restrict__ u_out, float* __restrict__ ub_out,
             float* __restrict__ p_out, float* __restrict__ q_out)
{
    constexpr int RR   = RRv(T);
    constexpr int NCG  = NCGv(T);
    constexpr int NACT = NACTv(T);
    constexpr int LSTR = LSTRv(T);

    // region row x lives at s_ub[.][x+1][.]
    __shared__ float s_ub[2][RR + 2][LSTR];

    const int t   = threadIdx.x;
    const int blk = blockIdx.x;            // 0..255
    // XCD-quad swizzle: blk%8==XCD heuristic. All 4 members of a 2x2 tile
    // quad share blk&7 -> one XCD; quad c covers tiles (2*(c>>1)+di,
    // 2*(c&1)+dj) of batch b. Bijection blk <-> (b,ti,tj).
    const int xc  = blk & 7;
    const int s_  = blk >> 3;
    const int m_  = s_ >> 3;               // member in quad (0..3)
    const int b   = s_ & 7;                // batch
    const int ti  = ((xc >> 1) << 1) | (m_ >> 1);   // 0..7
    const int tj  = ((xc & 1) << 1) | (m_ & 1);     // 0..3
    const int gi0 = ti * 32 - T;
    const int gj0 = tj * 64 - T;
    const int boff = b * (Hc * Wc);

    const bool active = (NACT == BLKv(T)) || (t < NACT);
    const int rp  = t / NCG;
    const int cgv = t - rp * NCG;
    const int r   = rp * 2;                // region row of top row
    const int c0  = cgv * 4;
    const int gi  = gi0 + r;               // global row of top row
    const int gj  = gj0 + c0;

    const float* fb = f + boff;
    const float* lb = lam + boff;

    float u[2][4], ub[2][4], p[2][4], q[2][4], bf[2][4];
    float pg[4], qg[2];                    // ghost p row (gi-1), ghost q col (gj-1)
    float bp[2][4], bpg[4], bq[2][4], bqg[2];

    // ---------------- load phase ----------------
    if (active) {
        float4 v0, v1;
        v0 = gld4(fb, gi, gj); v1 = gld4(fb, gi + 1, gj);
        bf[0][0] = Bq_ * v0.x; bf[0][1] = Bq_ * v0.y; bf[0][2] = Bq_ * v0.z; bf[0][3] = Bq_ * v0.w;
        bf[1][0] = Bq_ * v1.x; bf[1][1] = Bq_ * v1.y; bf[1][2] = Bq_ * v1.z; bf[1][3] = Bq_ * v1.w;
        const float4 fr0 = v0, fr1 = v1;

        // lam row gi (cols gj..gj+4), row gi+1, row gi+2
        float4 l0 = gld4(lb, gi, gj);     const float l04 = gld1(lb, gi, gj + 4);
        float4 l1 = gld4(lb, gi + 1, gj); const float l14 = gld1(lb, gi + 1, gj + 4);
        float4 l2 = gld4(lb, gi + 2, gj);
        bpg[0] = l0.x; bpg[1] = l0.y; bpg[2] = l0.z; bpg[3] = l0.w;   // ghost p bound = lam[gi]
        bq[0][0] = l0.y; bq[0][1] = l0.z; bq[0][2] = l0.w; bq[0][3] = l04;
        bqg[0] = l0.x;
        bp[0][0] = l1.x; bp[0][1] = l1.y; bp[0][2] = l1.z; bp[0][3] = l1.w;  // p row gi bound
        bq[1][0] = l1.y; bq[1][1] = l1.z; bq[1][2] = l1.w; bq[1][3] = l14;
        bqg[1] = l1.x;
        bp[1][0] = l2.x; bp[1][1] = l2.y; bp[1][2] = l2.z; bp[1][3] = l2.w;  // p row gi+1 bound

        // pad fixes: p at global row -1 == 0, q at global col -1 == 0;
        // their SHIFTED bounds are in-image there -> zero explicitly.
        if (gi     < 0) { bp[0][0] = bp[0][1] = bp[0][2] = bp[0][3] = 0.f; }
        if (gi + 1 < 0) { bp[1][0] = bp[1][1] = bp[1][2] = bp[1][3] = 0.f; }
        if (gi - 1 < 0) { bpg[0] = bpg[1] = bpg[2] = bpg[3] = 0.f; }
        #pragma unroll
        for (int e = 0; e < 4; ++e)
            if (gj + e < 0) { bq[0][e] = 0.f; bq[1][e] = 0.f; }
        if (gj - 1 < 0) { bqg[0] = 0.f; bqg[1] = 0.f; }

        if (FIRST) {
            u[0][0] = ub[0][0] = fr0.x; u[0][1] = ub[0][1] = fr0.y;
            u[0][2] = ub[0][2] = fr0.z; u[0][3] = ub[0][3] = fr0.w;
            u[1][0] = ub[1][0] = fr1.x; u[1][1] = ub[1][1] = fr1.y;
            u[1][2] = ub[1][2] = fr1.z; u[1][3] = ub[1][3] = fr1.w;
            #pragma unroll
            for (int e = 0; e < 4; ++e) { p[0][e] = p[1][e] = q[0][e] = q[1][e] = pg[e] = 0.f; }
            qg[0] = qg[1] = 0.f;
        } else {
            #pragma unroll
            for (int row = 0; row < 2; ++row) {
                v0 = gld4(u_in + boff, gi + row, gj);
                u[row][0] = v0.x; u[row][1] = v0.y; u[row][2] = v0.z; u[row][3] = v0.w;
                v0 = gld4(ub_in + boff, gi + row, gj);
                ub[row][0] = v0.x; ub[row][1] = v0.y; ub[row][2] = v0.z; ub[row][3] = v0.w;
                v0 = gld4(p_in + boff, gi + row, gj);
                p[row][0] = v0.x; p[row][1] = v0.y; p[row][2] = v0.z; p[row][3] = v0.w;
                v0 = gld4(q_in + boff, gi + row, gj);
                q[row][0] = v0.x; q[row][1] = v0.y; q[row][2] = v0.z; q[row][3] = v0.w;
            }
            v0 = gld4(p_in + boff, gi - 1, gj);
            pg[0] = v0.x; pg[1] = v0.y; pg[2] = v0.z; pg[3] = v0.w;
            qg[0] = gld1(q_in + boff, gi,     gj - 1);
            qg[1] = gld1(q_in + boff, gi + 1, gj - 1);
        }

        *(float4*)&s_ub[0][r + 1][c0] = make_float4(ub[0][0], ub[0][1], ub[0][2], ub[0][3]);
        *(float4*)&s_ub[0][r + 2][c0] = make_float4(ub[1][0], ub[1][1], ub[1][2], ub[1][3]);
    }
    __syncthreads();

    // ---------------- T fused iterations, 1 barrier each ----------------
    auto iter_step = [&](int cur) {
        const int nxt = cur ^ 1;
        if (active) {
            const float4 ubm1 = *(const float4*)&s_ub[cur][r][c0];      // row r-1
            const float4 ubp2 = *(const float4*)&s_ub[cur][r + 3][c0];  // row r+2
            const float  ubre0 = s_ub[cur][r + 1][c0 + 4];
            const float  ubre1 = s_ub[cur][r + 2][c0 + 4];
            const float  uble0 = s_ub[cur][r + 1][c0 - 1];
            const float  uble1 = s_ub[cur][r + 2][c0 - 1];

            // ---- step 1: p, q, ghosts (from prev-iter ubar) ----
            pg[0] = clipf(fmaf(SIGc, ub[0][0] - ubm1.x, pg[0]), bpg[0]);
            pg[1] = clipf(fmaf(SIGc, ub[0][1] - ubm1.y, pg[1]), bpg[1]);
            pg[2] = clipf(fmaf(SIGc, ub[0][2] - ubm1.z, pg[2]), bpg[2]);
            pg[3] = clipf(fmaf(SIGc, ub[0][3] - ubm1.w, pg[3]), bpg[3]);

            p[0][0] = clipf(fmaf(SIGc, ub[1][0] - ub[0][0], p[0][0]), bp[0][0]);
            p[0][1] = clipf(fmaf(SIGc, ub[1][1] - ub[0][1], p[0][1]), bp[0][1]);
            p[0][2] = clipf(fmaf(SIGc, ub[1][2] - ub[0][2], p[0][2]), bp[0][2]);
            p[0][3] = clipf(fmaf(SIGc, ub[1][3] - ub[0][3], p[0][3]), bp[0][3]);

            p[1][0] = clipf(fmaf(SIGc, ubp2.x - ub[1][0], p[1][0]), bp[1][0]);
            p[1][1] = clipf(fmaf(SIGc, ubp2.y - ub[1][1], p[1][1]), bp[1][1]);
            p[1][2] = clipf(fmaf(SIGc, ubp2.z - ub[1][2], p[1][2]), bp[1][2]);
            p[1][3] = clipf(fmaf(SIGc, ubp2.w - ub[1][3], p[1][3]), bp[1][3]);

            qg[0] = clipf(fmaf(SIGc, ub[0][0] - uble0, qg[0]), bqg[0]);
            qg[1] = clipf(fmaf(SIGc, ub[1][0] - uble1, qg[1]), bqg[1]);

            q[0][0] = clipf(fmaf(SIGc, ub[0][1] - ub[0][0], q[0][0]), bq[0][0]);
            q[0][1] = clipf(fmaf(SIGc, ub[0][2] - ub[0][1], q[0][1]), bq[0][1]);
            q[0][2] = clipf(fmaf(SIGc, ub[0][3] - ub[0][2], q[0][2]), bq[0][2]);
            q[0][3] = clipf(fmaf(SIGc, ubre0    - ub[0][3], q[0][3]), bq[0][3]);

            q[1][0] = clipf(fmaf(SIGc, ub[1][1] - ub[1][0], q[1][0]), bq[1][0]);
            q[1][1] = clipf(fmaf(SIGc, ub[1][2] - ub[1][1], q[1][1]), bq[1][1]);
            q[1][2] = clipf(fmaf(SIGc, ub[1][3] - ub[1][2], q[1][2]), bq[1][2]);
            q[1][3] = clipf(fmaf(SIGc, ubre1    - ub[1][3], q[1][3]), bq[1][3]);

            // ---- step 2: u, ubar ----
            float dv, un;
            dv = (pg[0] - p[0][0]) + (qg[0]   - q[0][0]);
            un = fmaf(-Bq_, dv, fmaf(Ac_, u[0][0], bf[0][0]));
            ub[0][0] = 2.f * un - u[0][0]; u[0][0] = un;
            dv = (pg[1] - p[0][1]) + (q[0][0] - q[0][1]);
            un = fmaf(-Bq_, dv, fmaf(Ac_, u[0][1], bf[0][1]));
            ub[0][1] = 2.f * un - u[0][1]; u[0][1] = un;
            dv = (pg[2] - p[0][2]) + (q[0][1] - q[0][2]);
            un = fmaf(-Bq_, dv, fmaf(Ac_, u[0][2], bf[0][2]));
            ub[0][2] = 2.f * un - u[0][2]; u[0][2] = un;
            dv = (pg[3] - p[0][3]) + (q[0][2] - q[0][3]);
            un = fmaf(-Bq_, dv, fmaf(Ac_, u[0][3], bf[0][3]));
            ub[0][3] = 2.f * un - u[0][3]; u[0][3] = un;

            dv = (p[0][0] - p[1][0]) + (qg[1]   - q[1][0]);
            un = fmaf(-Bq_, dv, fmaf(Ac_, u[1][0], bf[1][0]));
            ub[1][0] = 2.f * un - u[1][0]; u[1][0] = un;
            dv = (p[0][1] - p[1][1]) + (q[1][0] - q[1][1]);
            un = fmaf(-Bq_, dv, fmaf(Ac_, u[1][1], bf[1][1]));
            ub[1][1] = 2.f * un - u[1][1]; u[1][1] = un;
            dv = (p[0][2] - p[1][2]) + (q[1][1] - q[1][2]);
            un = fmaf(-Bq_, dv, fmaf(Ac_, u[1][2], bf[1][2]));
            ub[1][2] = 2.f * un - u[1][2]; u[1][2] = un;
            dv = (p[0][3] - p[1][3]) + (q[1][2] - q[1][3]);
            un = fmaf(-Bq_, dv, fmaf(Ac_, u[1][3], bf[1][3]));
            ub[1][3] = 2.f * un - u[1][3]; u[1][3] = un;

            *(float4*)&s_ub[nxt][r + 1][c0] = make_float4(ub[0][0], ub[0][1], ub[0][2], ub[0][3]);
            *(float4*)&s_ub[nxt][r + 2][c0] = make_float4(ub[1][0], ub[1][1], ub[1][2], ub[1][3]);
        }
        __syncthreads();
    };

    for (int kk = 0; kk < T / 2; ++kk) { iter_step(0); iter_step(1); }

    // ---------------- store phase (interior only) ----------------
    if (active && r >= T && r < T + 32 && cgv >= T / 4 && cgv < T / 4 + 16) {
        const int idx0 = boff + (gi << 8) + gj;
        const int idx1 = idx0 + Wc;
        if (LAST) {
            *(float4*)&u_out[idx0] = make_float4(u[0][0], u[0][1], u[0][2], u[0][3]);
            *(float4*)&u_out[idx1] = make_float4(u[1][0], u[1][1], u[1][2], u[1][3]);
        } else {
            *(float4*)&u_out [idx0] = make_float4(u[0][0],  u[0][1],  u[0][2],  u[0][3]);
            *(float4*)&u_out [idx1] = make_float4(u[1][0],  u[1][1],  u[1][2],  u[1][3]);
            *(float4*)&ub_out[idx0] = make_float4(ub[0][0], ub[0][1], ub[0][2], ub[0][3]);
            *(float4*)&ub_out[idx1] = make_float4(ub[1][0], ub[1][1], ub[1][2], ub[1][3]);
            *(float4*)&p_out [idx0] = make_float4(p[0][0],  p[0][1],  p[0][2],  p[0][3]);
            *(float4*)&p_out [idx1] = make_float4(p[1][0],  p[1][1],  p[1][2],  p[1][3]);
            *(float4*)&q_out [idx0] = make_float4(q[0][0],  q[0][1],  q[0][2],  q[0][3]);
            *(float4*)&q_out [idx1] = make_float4(q[1][0],  q[1][1],  q[1][2],  q[1][3]);
        }
    }
}

extern "C" void kernel_launch(void* const* d_in, const int* in_sizes, int n_in,
                              void* d_out, int out_size, void* d_ws, size_t ws_size,
                              hipStream_t stream)
{
    const float* f   = (const float*)d_in[0];
    const float* lam = (const float*)d_in[1];
    float* ws = (float*)d_ws;

    float* U [2] = { ws + 0 * (size_t)NPIX, ws + 4 * (size_t)NPIX };
    float* UB[2] = { ws + 1 * (size_t)NPIX, ws + 5 * (size_t)NPIX };
    float* P [2] = { ws + 2 * (size_t)NPIX, ws + 6 * (size_t)NPIX };
    float* Q [2] = { ws + 3 * (size_t)NPIX, ws + 7 * (size_t)NPIX };

    dim3 grid(256);

    // 12 launches of T=16 (iters 0..191) + 1 launch of T=8 (iters 192..199)
    tv_tile<16, true, false><<<grid, dim3(BLKv(16)), 0, stream>>>(
        f, lam, nullptr, nullptr, nullptr, nullptr,
        U[0], UB[0], P[0], Q[0]);

    for (int l = 1; l < 12; ++l) {
        const int w = l & 1, r = w ^ 1;
        tv_tile<16, false, false><<<grid, dim3(BLKv(16)), 0, stream>>>(
            f, lam, U[r], UB[r], P[r], Q[r],
            U[w], UB[w], P[w], Q[w]);
    }

    // launch 11 wrote set 1; final T=8 launch reads set 1, writes u -> d_out
    tv_tile<8, false, true><<<grid, dim3(BLKv(8)), 0, stream>>>(
        f, lam, U[1], UB[1], P[1], Q[1],
        (float*)d_out, nullptr, nullptr, nullptr);
}

// Round 9
// 249.145 us; speedup vs baseline: 11.0853x; 1.0750x over previous
//
#include <hip/hip_runtime.h>

// Chambolle-Pock anisotropic TV prox. B=8, H=W=256, 200 iters, fp32.
//
// Round 9: round-8 structure (T=16 x12 + T=8 x1, 2x4 patch/thread,
// ubar-only fp32 LDS dbuf, register ghosts, med3 clamp, XCD-quad swizzle)
// + fp16 INTER-LAUNCH state: the u/ub/p/q ping-pong arrays in ws are
// _Float16 (SoA). All in-launch arithmetic and LDS stay fp32; only the
// launch-boundary exchange is quantized (~5e-4/field/boundary, 12
// boundaries, contraction-damped -> ~5e-3 added error vs 7e-2 threshold).
// Halves the ~33 MB/launch state traffic and its instruction count.
// Boundary semantics (r3/r6-verified): OOB lam -> 0 -> p,q clamp to 0;
// explicitly zero SHIFTED bounds at pads (p[-1]: bp/bpg when row<0;
// q[:,-1]: bq/bqg when col<0). LDS edge garbage advances 1 cell/iter,
// reaches (never enters) interior after T iters; med3 scrubs NaN.

#define Hc 256
#define Wc 256
#define Bc 8
#define NPIX (Bc * Hc * Wc)          // 524288

typedef _Float16 half4_ __attribute__((ext_vector_type(4)));

constexpr int RRv(int T)   { return 32 + 2 * T; }          // region rows
constexpr int RCv(int T)   { return 64 + 2 * T; }          // region cols
constexpr int NCGv(int T)  { return RCv(T) / 4; }          // col groups
constexpr int NACTv(int T) { return (RRv(T) / 2) * NCGv(T); }
constexpr int BLKv(int T)  { return (NACTv(T) + 63) / 64 * 64; }
constexpr int LSTRv(int T) { return (RCv(T) + 2 + 3) / 4 * 4; }  // 16B-mult row stride

constexpr float TAUc = 0.35355339f;
constexpr float SIGc = 0.35355339f;
constexpr float Ac_  = 1.0f / (1.0f + TAUc);
constexpr float Bq_  = TAUc * Ac_;

__device__ __forceinline__ float4 gld4(const float* p, int gi, int gj) {
    if ((unsigned)gi < (unsigned)Hc && (unsigned)gj < (unsigned)Wc)
        return *(const float4*)(p + (gi << 8) + gj);
    return make_float4(0.f, 0.f, 0.f, 0.f);
}
__device__ __forceinline__ float gld1(const float* p, int gi, int gj) {
    if ((unsigned)gi < (unsigned)Hc && (unsigned)gj < (unsigned)Wc)
        return p[(gi << 8) + gj];
    return 0.f;
}
__device__ __forceinline__ half4_ gld4h(const _Float16* p, int gi, int gj) {
    if ((unsigned)gi < (unsigned)Hc && (unsigned)gj < (unsigned)Wc)
        return *(const half4_*)(p + (gi << 8) + gj);
    return half4_{(_Float16)0.f, (_Float16)0.f, (_Float16)0.f, (_Float16)0.f};
}
__device__ __forceinline__ float gld1h(const _Float16* p, int gi, int gj) {
    if ((unsigned)gi < (unsigned)Hc && (unsigned)gj < (unsigned)Wc)
        return (float)p[(gi << 8) + gj];
    return 0.f;
}
// clamp to [-b, b] in one v_med3_f32; NaN v -> -b (finite, 0 when b==0).
__device__ __forceinline__ float clipf(float v, float b) {
    return __builtin_amdgcn_fmed3f(v, -b, b);
}
__device__ __forceinline__ half4_ toh4(const float* v) {
    return half4_{(_Float16)v[0], (_Float16)v[1], (_Float16)v[2], (_Float16)v[3]};
}

template <int T, bool FIRST, bool LAST>
__global__ __launch_bounds__(BLKv(T))
void tv_tile(const float* __restrict__ f, const float* __restrict__ lam,
             const _Float16* __restrict__ u_in, const _Float16* __restrict__ ub_in,
             const _Float16* __restrict__ p_in, const _Float16* __restrict__ q_in,
             _Float16* __restrict__ u_out, _Float16* __restrict__ ub_out,
             _Float16* __restrict__ p_out, _Float16* __restrict__ q_out,
             float* __restrict__ fin_out)
{
    constexpr int RR   = RRv(T);
    constexpr int NCG  = NCGv(T);
    constexpr int NACT = NACTv(T);
    constexpr int LSTR = LSTRv(T);

    __shared__ float s_ub[2][RR + 2][LSTR];   // region row x at [.][x+1][.]

    const int t   = threadIdx.x;
    const int blk = blockIdx.x;            // 0..255
    // XCD-quad swizzle: all 4 members of a 2x2 tile quad share blk&7 (XCD).
    const int xc  = blk & 7;
    const int s_  = blk >> 3;
    const int m_  = s_ >> 3;               // member in quad (0..3)
    const int b   = s_ & 7;                // batch
    const int ti  = ((xc >> 1) << 1) | (m_ >> 1);   // 0..7
    const int tj  = ((xc & 1) << 1) | (m_ & 1);     // 0..3
    const int gi0 = ti * 32 - T;
    const int gj0 = tj * 64 - T;
    const int boff = b * (Hc * Wc);

    const bool active = (NACT == BLKv(T)) || (t < NACT);
    const int rp  = t / NCG;
    const int cgv = t - rp * NCG;
    const int r   = rp * 2;                // region row of top row
    const int c0  = cgv * 4;
    const int gi  = gi0 + r;               // global row of top row
    const int gj  = gj0 + c0;

    const float* fb = f + boff;
    const float* lb = lam + boff;

    float u[2][4], ub[2][4], p[2][4], q[2][4], bf[2][4];
    float pg[4], qg[2];                    // ghost p row (gi-1), ghost q col (gj-1)
    float bp[2][4], bpg[4], bq[2][4], bqg[2];

    // ---------------- load phase ----------------
    if (active) {
        float4 v0, v1;
        v0 = gld4(fb, gi, gj); v1 = gld4(fb, gi + 1, gj);
        bf[0][0] = Bq_ * v0.x; bf[0][1] = Bq_ * v0.y; bf[0][2] = Bq_ * v0.z; bf[0][3] = Bq_ * v0.w;
        bf[1][0] = Bq_ * v1.x; bf[1][1] = Bq_ * v1.y; bf[1][2] = Bq_ * v1.z; bf[1][3] = Bq_ * v1.w;
        const float4 fr0 = v0, fr1 = v1;

        float4 l0 = gld4(lb, gi, gj);     const float l04 = gld1(lb, gi, gj + 4);
        float4 l1 = gld4(lb, gi + 1, gj); const float l14 = gld1(lb, gi + 1, gj + 4);
        float4 l2 = gld4(lb, gi + 2, gj);
        bpg[0] = l0.x; bpg[1] = l0.y; bpg[2] = l0.z; bpg[3] = l0.w;   // ghost p bound = lam[gi]
        bq[0][0] = l0.y; bq[0][1] = l0.z; bq[0][2] = l0.w; bq[0][3] = l04;
        bqg[0] = l0.x;
        bp[0][0] = l1.x; bp[0][1] = l1.y; bp[0][2] = l1.z; bp[0][3] = l1.w;  // p row gi bound
        bq[1][0] = l1.y; bq[1][1] = l1.z; bq[1][2] = l1.w; bq[1][3] = l14;
        bqg[1] = l1.x;
        bp[1][0] = l2.x; bp[1][1] = l2.y; bp[1][2] = l2.z; bp[1][3] = l2.w;  // p row gi+1 bound

        // pad fixes: p[-1,:]=0 and q[:,-1]=0 in the reference; their
        // SHIFTED bounds are in-image there -> zero explicitly.
        if (gi     < 0) { bp[0][0] = bp[0][1] = bp[0][2] = bp[0][3] = 0.f; }
        if (gi + 1 < 0) { bp[1][0] = bp[1][1] = bp[1][2] = bp[1][3] = 0.f; }
        if (gi - 1 < 0) { bpg[0] = bpg[1] = bpg[2] = bpg[3] = 0.f; }
        #pragma unroll
        for (int e = 0; e < 4; ++e)
            if (gj + e < 0) { bq[0][e] = 0.f; bq[1][e] = 0.f; }
        if (gj - 1 < 0) { bqg[0] = 0.f; bqg[1] = 0.f; }

        if (FIRST) {
            u[0][0] = ub[0][0] = fr0.x; u[0][1] = ub[0][1] = fr0.y;
            u[0][2] = ub[0][2] = fr0.z; u[0][3] = ub[0][3] = fr0.w;
            u[1][0] = ub[1][0] = fr1.x; u[1][1] = ub[1][1] = fr1.y;
            u[1][2] = ub[1][2] = fr1.z; u[1][3] = ub[1][3] = fr1.w;
            #pragma unroll
            for (int e = 0; e < 4; ++e) { p[0][e] = p[1][e] = q[0][e] = q[1][e] = pg[e] = 0.f; }
            qg[0] = qg[1] = 0.f;
        } else {
            half4_ hv;
            #pragma unroll
            for (int row = 0; row < 2; ++row) {
                hv = gld4h(u_in + boff, gi + row, gj);
                u[row][0] = hv.x; u[row][1] = hv.y; u[row][2] = hv.z; u[row][3] = hv.w;
                hv = gld4h(ub_in + boff, gi + row, gj);
                ub[row][0] = hv.x; ub[row][1] = hv.y; ub[row][2] = hv.z; ub[row][3] = hv.w;
                hv = gld4h(p_in + boff, gi + row, gj);
                p[row][0] = hv.x; p[row][1] = hv.y; p[row][2] = hv.z; p[row][3] = hv.w;
                hv = gld4h(q_in + boff, gi + row, gj);
                q[row][0] = hv.x; q[row][1] = hv.y; q[row][2] = hv.z; q[row][3] = hv.w;
            }
            hv = gld4h(p_in + boff, gi - 1, gj);
            pg[0] = hv.x; pg[1] = hv.y; pg[2] = hv.z; pg[3] = hv.w;
            qg[0] = gld1h(q_in + boff, gi,     gj - 1);
            qg[1] = gld1h(q_in + boff, gi + 1, gj - 1);
        }

        *(float4*)&s_ub[0][r + 1][c0] = make_float4(ub[0][0], ub[0][1], ub[0][2], ub[0][3]);
        *(float4*)&s_ub[0][r + 2][c0] = make_float4(ub[1][0], ub[1][1], ub[1][2], ub[1][3]);
    }
    __syncthreads();

    // ---------------- T fused iterations, 1 barrier each ----------------
    auto iter_step = [&](int cur) {
        const int nxt = cur ^ 1;
        if (active) {
            const float4 ubm1 = *(const float4*)&s_ub[cur][r][c0];      // row r-1
            const float4 ubp2 = *(const float4*)&s_ub[cur][r + 3][c0];  // row r+2
            const float  ubre0 = s_ub[cur][r + 1][c0 + 4];
            const float  ubre1 = s_ub[cur][r + 2][c0 + 4];
            const float  uble0 = s_ub[cur][r + 1][c0 - 1];
            const float  uble1 = s_ub[cur][r + 2][c0 - 1];

            // ---- step 1: p, q, ghosts (from prev-iter ubar) ----
            pg[0] = clipf(fmaf(SIGc, ub[0][0] - ubm1.x, pg[0]), bpg[0]);
            pg[1] = clipf(fmaf(SIGc, ub[0][1] - ubm1.y, pg[1]), bpg[1]);
            pg[2] = clipf(fmaf(SIGc, ub[0][2] - ubm1.z, pg[2]), bpg[2]);
            pg[3] = clipf(fmaf(SIGc, ub[0][3] - ubm1.w, pg[3]), bpg[3]);

            p[0][0] = clipf(fmaf(SIGc, ub[1][0] - ub[0][0], p[0][0]), bp[0][0]);
            p[0][1] = clipf(fmaf(SIGc, ub[1][1] - ub[0][1], p[0][1]), bp[0][1]);
            p[0][2] = clipf(fmaf(SIGc, ub[1][2] - ub[0][2], p[0][2]), bp[0][2]);
            p[0][3] = clipf(fmaf(SIGc, ub[1][3] - ub[0][3], p[0][3]), bp[0][3]);

            p[1][0] = clipf(fmaf(SIGc, ubp2.x - ub[1][0], p[1][0]), bp[1][0]);
            p[1][1] = clipf(fmaf(SIGc, ubp2.y - ub[1][1], p[1][1]), bp[1][1]);
            p[1][2] = clipf(fmaf(SIGc, ubp2.z - ub[1][2], p[1][2]), bp[1][2]);
            p[1][3] = clipf(fmaf(SIGc, ubp2.w - ub[1][3], p[1][3]), bp[1][3]);

            qg[0] = clipf(fmaf(SIGc, ub[0][0] - uble0, qg[0]), bqg[0]);
            qg[1] = clipf(fmaf(SIGc, ub[1][0] - uble1, qg[1]), bqg[1]);

            q[0][0] = clipf(fmaf(SIGc, ub[0][1] - ub[0][0], q[0][0]), bq[0][0]);
            q[0][1] = clipf(fmaf(SIGc, ub[0][2] - ub[0][1], q[0][1]), bq[0][1]);
            q[0][2] = clipf(fmaf(SIGc, ub[0][3] - ub[0][2], q[0][2]), bq[0][2]);
            q[0][3] = clipf(fmaf(SIGc, ubre0    - ub[0][3], q[0][3]), bq[0][3]);

            q[1][0] = clipf(fmaf(SIGc, ub[1][1] - ub[1][0], q[1][0]), bq[1][0]);
            q[1][1] = clipf(fmaf(SIGc, ub[1][2] - ub[1][1], q[1][1]), bq[1][1]);
            q[1][2] = clipf(fmaf(SIGc, ub[1][3] - ub[1][2], q[1][2]), bq[1][2]);
            q[1][3] = clipf(fmaf(SIGc, ubre1    - ub[1][3], q[1][3]), bq[1][3]);

            // ---- step 2: u, ubar ----
            float dv, un;
            dv = (pg[0] - p[0][0]) + (qg[0]   - q[0][0]);
            un = fmaf(-Bq_, dv, fmaf(Ac_, u[0][0], bf[0][0]));
            ub[0][0] = 2.f * un - u[0][0]; u[0][0] = un;
            dv = (pg[1] - p[0][1]) + (q[0][0] - q[0][1]);
            un = fmaf(-Bq_, dv, fmaf(Ac_, u[0][1], bf[0][1]));
            ub[0][1] = 2.f * un - u[0][1]; u[0][1] = un;
            dv = (pg[2] - p[0][2]) + (q[0][1] - q[0][2]);
            un = fmaf(-Bq_, dv, fmaf(Ac_, u[0][2], bf[0][2]));
            ub[0][2] = 2.f * un - u[0][2]; u[0][2] = un;
            dv = (pg[3] - p[0][3]) + (q[0][2] - q[0][3]);
            un = fmaf(-Bq_, dv, fmaf(Ac_, u[0][3], bf[0][3]));
            ub[0][3] = 2.f * un - u[0][3]; u[0][3] = un;

            dv = (p[0][0] - p[1][0]) + (qg[1]   - q[1][0]);
            un = fmaf(-Bq_, dv, fmaf(Ac_, u[1][0], bf[1][0]));
            ub[1][0] = 2.f * un - u[1][0]; u[1][0] = un;
            dv = (p[0][1] - p[1][1]) + (q[1][0] - q[1][1]);
            un = fmaf(-Bq_, dv, fmaf(Ac_, u[1][1], bf[1][1]));
            ub[1][1] = 2.f * un - u[1][1]; u[1][1] = un;
            dv = (p[0][2] - p[1][2]) + (q[1][1] - q[1][2]);
            un = fmaf(-Bq_, dv, fmaf(Ac_, u[1][2], bf[1][2]));
            ub[1][2] = 2.f * un - u[1][2]; u[1][2] = un;
            dv = (p[0][3] - p[1][3]) + (q[1][2] - q[1][3]);
            un = fmaf(-Bq_, dv, fmaf(Ac_, u[1][3], bf[1][3]));
            ub[1][3] = 2.f * un - u[1][3]; u[1][3] = un;

            *(float4*)&s_ub[nxt][r + 1][c0] = make_float4(ub[0][0], ub[0][1], ub[0][2], ub[0][3]);
            *(float4*)&s_ub[nxt][r + 2][c0] = make_float4(ub[1][0], ub[1][1], ub[1][2], ub[1][3]);
        }
        __syncthreads();
    };

    for (int kk = 0; kk < T / 2; ++kk) { iter_step(0); iter_step(1); }

    // ---------------- store phase (interior only) ----------------
    if (active && r >= T && r < T + 32 && cgv >= T / 4 && cgv < T / 4 + 16) {
        const int idx0 = boff + (gi << 8) + gj;
        const int idx1 = idx0 + Wc;
        if (LAST) {
            *(float4*)&fin_out[idx0] = make_float4(u[0][0], u[0][1], u[0][2], u[0][3]);
            *(float4*)&fin_out[idx1] = make_float4(u[1][0], u[1][1], u[1][2], u[1][3]);
        } else {
            *(half4_*)&u_out [idx0] = toh4(u[0]);
            *(half4_*)&u_out [idx1] = toh4(u[1]);
            *(half4_*)&ub_out[idx0] = toh4(ub[0]);
            *(half4_*)&ub_out[idx1] = toh4(ub[1]);
            *(half4_*)&p_out [idx0] = toh4(p[0]);
            *(half4_*)&p_out [idx1] = toh4(p[1]);
            *(half4_*)&q_out [idx0] = toh4(q[0]);
            *(half4_*)&q_out [idx1] = toh4(q[1]);
        }
    }
}

extern "C" void kernel_launch(void* const* d_in, const int* in_sizes, int n_in,
                              void* d_out, int out_size, void* d_ws, size_t ws_size,
                              hipStream_t stream)
{
    const float* f   = (const float*)d_in[0];
    const float* lam = (const float*)d_in[1];
    _Float16* ws = (_Float16*)d_ws;      // 8 half arrays = 8 MB

    _Float16* U [2] = { ws + 0 * (size_t)NPIX, ws + 4 * (size_t)NPIX };
    _Float16* UB[2] = { ws + 1 * (size_t)NPIX, ws + 5 * (size_t)NPIX };
    _Float16* P [2] = { ws + 2 * (size_t)NPIX, ws + 6 * (size_t)NPIX };
    _Float16* Q [2] = { ws + 3 * (size_t)NPIX, ws + 7 * (size_t)NPIX };

    dim3 grid(256);

    // 12 launches of T=16 (iters 0..191) + 1 launch of T=8 (iters 192..199)
    tv_tile<16, true, false><<<grid, dim3(BLKv(16)), 0, stream>>>(
        f, lam, nullptr, nullptr, nullptr, nullptr,
        U[0], UB[0], P[0], Q[0], nullptr);

    for (int l = 1; l < 12; ++l) {
        const int w = l & 1, r = w ^ 1;
        tv_tile<16, false, false><<<grid, dim3(BLKv(16)), 0, stream>>>(
            f, lam, U[r], UB[r], P[r], Q[r],
            U[w], UB[w], P[w], Q[w], nullptr);
    }

    // launch 11 wrote set 1; final T=8 launch reads set 1, writes u -> d_out
    tv_tile<8, false, true><<<grid, dim3(BLKv(8)), 0, stream>>>(
        f, lam, U[1], UB[1], P[1], Q[1],
        nullptr, nullptr, nullptr, nullptr, (float*)d_out);
}